// Round 4
// baseline (175.636 us; speedup 1.0000x reference)
//
#include <hip/hip_runtime.h>
#include <math.h>

#define Bc 8
#define Nseq 512
#define DM 512
#define Hh 8
#define NUMREL 1023
#define ZOFF 511   // NUMREL/2
#define STR 552    // pstrip row stride (shorts)

typedef _Float16 half8 __attribute__((ext_vector_type(8)));
typedef float f32x4 __attribute__((ext_vector_type(4)));

__device__ __forceinline__ unsigned short f2h(float f) {
  _Float16 h = (_Float16)f;  // v_cvt_f16_f32, RNE
  return __builtin_bit_cast(unsigned short, h);
}

typedef __attribute__((address_space(3))) unsigned int as3_uint;
typedef __attribute__((address_space(1))) const unsigned int as1_uint;
__device__ __forceinline__ void gl_lds16(const void* g, void* l) {
  __builtin_amdgcn_global_load_lds((as1_uint*)g, (as3_uint*)l, 16, 0, 0);
}

// ---------------------------------------------------------------------------
// DIAGNOSTIC ROUND: grids multiplied (prep x4, qkv x4, final x6) with bid%N
// clone mapping — clones recompute identical outputs (idempotent, race-free).
// Pushes each kernel's single-dispatch duration past the ~45us top-5 cutoff
// so rocprof exposes per-kernel counters. attn unchanged (known: ~24us).
// ---------------------------------------------------------------------------

// prep_all: bid [0,1024) X->XbF; [1024,2048) W->W*F; [2048,2088) Pk->Pkt;
// [2088,2216) Pv->PvF2.
__global__ __launch_bounds__(256) void prep_all(
    const float* __restrict__ X, const float* __restrict__ Wq,
    const float* __restrict__ Wk, const float* __restrict__ Wv,
    const float* __restrict__ Wo, const float* __restrict__ Pk,
    const float* __restrict__ Pv,
    unsigned short* __restrict__ XbF, unsigned short* __restrict__ WqF,
    unsigned short* __restrict__ WkF, unsigned short* __restrict__ WvF,
    unsigned short* __restrict__ WoF,
    float* __restrict__ Pkt, unsigned short* __restrict__ PvF2) {
  __shared__ float tbuf[5120];
  const int bid = blockIdx.x % 2216;  // clone mapping (diagnostic)
  const int tid = threadIdx.x;

  if (bid < 1024) {
    const int w = tid >> 6, lane = tid & 63;
    const int r = bid * 4 + w;
    const float* src = X + (size_t)r * DM + lane * 8;
    float4 a = *(const float4*)src;
    float4 b = *(const float4*)(src + 4);
    ushort4 o0, o1;
    o0.x = f2h(a.x); o0.y = f2h(a.y); o0.z = f2h(a.z); o0.w = f2h(a.w);
    o1.x = f2h(b.x); o1.y = f2h(b.y); o1.z = f2h(b.z); o1.w = f2h(b.w);
    const int mc = r >> 4, kf = lane >> 2, l = (lane & 3) * 16 + (r & 15);
    size_t flat = (((size_t)mc * 16 + kf) * 64 + l) * 8;
    *(ushort4*)(XbF + flat) = o0;
    *(ushort4*)(XbF + flat + 4) = o1;
  } else if (bid < 2048) {
    const int idx = bid - 1024;
    const int z = idx >> 8, r256 = idx & 255;
    const int bx = r256 & 15, by = r256 >> 4;
    const float* src = z == 0 ? Wq : z == 1 ? Wk : z == 2 ? Wv : Wo;
    unsigned short* dst = z == 0 ? WqF : z == 1 ? WkF : z == 2 ? WvF : WoF;
    const int k0 = by * 32, n0 = bx * 32;
#pragma unroll
    for (int u = 0; u < 4; ++u) {
      int i2 = u * 256 + tid, r = i2 >> 5, c = i2 & 31;
      tbuf[r * 33 + c] = src[(size_t)(k0 + r) * DM + n0 + c];
    }
    __syncthreads();
    const int ncl = tid >> 7, l = (tid >> 1) & 63, eh = tid & 1;
    const int nl = ncl * 16 + (l & 15);
    const int klb = (l >> 4) * 8 + eh * 4;
    ushort4 o;
    o.x = f2h(tbuf[(klb + 0) * 33 + nl]);
    o.y = f2h(tbuf[(klb + 1) * 33 + nl]);
    o.z = f2h(tbuf[(klb + 2) * 33 + nl]);
    o.w = f2h(tbuf[(klb + 3) * 33 + nl]);
    size_t flat = (((size_t)((n0 >> 4) + ncl) * 16 + (k0 >> 5)) * 64 + l) * 8 + eh * 4;
    *(ushort4*)(dst + flat) = o;
  } else if (bid < 2088) {
    const int idx = bid - 2048;
    const int gx = idx % 5, h = idx / 5;
    const int g = gx * 256 + tid;
    if (g < 1040)
      Pkt[(size_t)h * 1040 + g] = (g < NUMREL) ? Pk[(size_t)g * Hh + h] : 0.f;
  } else {
    const int idx = bid - 2088;
    const int gx = idx & 15, h = idx >> 4;
    const int g0 = gx * 64;
#pragma unroll
    for (int u = 0; u < 20; ++u) {
      int i2 = u * 256 + tid, r = i2 >> 6, c = i2 & 63;
      int g = g0 + r;
      tbuf[r * 64 + c] = (g < NUMREL) ? Pv[(size_t)g * 512 + h * 64 + c] : 0.f;
    }
    __syncthreads();
#pragma unroll
    for (int av = 0; av < 2; ++av)
#pragma unroll
      for (int gtl = 0; gtl < 2; ++gtl) {
        int gt = (g0 >> 5) + gtl;
#pragma unroll
        for (int dt = 0; dt < 4; ++dt) {
          size_t base = ((((size_t)av * Hh + h) * 4 + dt) * 32 + gt) * 512;
          int i2 = tid * 2;
          int l = i2 >> 3, e = i2 & 7;
          int gr = av * 16 + gtl * 32 + (l >> 4) * 8 + e;
          int dcol = dt * 16 + (l & 15);
          ushort2 o;
          o.x = f2h(tbuf[gr * 64 + dcol]);
          o.y = f2h(tbuf[(gr + 1) * 64 + dcol]);
          *(ushort2*)(PvF2 + base + i2) = o;
        }
      }
  }
}

// ---------------------------------------------------------------------------
// gemm_qkv: z-fused fp16 MFMA, frag-major, BK=64 staged.
// ---------------------------------------------------------------------------
__global__ __launch_bounds__(256, 2) void gemm_qkv(const unsigned short* __restrict__ XbF,
                                                   const unsigned short* __restrict__ WqF,
                                                   const unsigned short* __restrict__ WkF,
                                                   const unsigned short* __restrict__ WvF,
                                                   const float* __restrict__ bq,
                                                   const float* __restrict__ bk,
                                                   const float* __restrict__ bv,
                                                   unsigned short* __restrict__ Qb,
                                                   unsigned short* __restrict__ KF,
                                                   unsigned short* __restrict__ VF) {
  const int flat = blockIdx.x & 511;  // clone mapping (diagnostic)
  const int xcd = flat & 7, g = flat >> 3;
  const int by = xcd * 8 + (g & 7), bx = g >> 3;
  const int bm = by * 64, bn = bx * 64;
  const int mc0 = bm >> 4, nc0 = bn >> 4;
  const int tid = threadIdx.x, w = tid >> 6, lane = tid & 63;
  const int lo = lane & 15, quad = lane >> 4;
  const int mh = (w >> 1) * 2, nh = (w & 1) * 2;

  __shared__ __align__(16) unsigned short stg[2][32 * 512];

  const unsigned short* srcArr = w == 0 ? XbF : w == 1 ? WqF : w == 2 ? WkF : WvF;
  const int rowbase = (w == 0) ? mc0 : nc0;

#define STAGE(buf, ks)                                                             \
  do {                                                                             \
    _Pragma("unroll") for (int t = 0; t < 8; ++t) {                                \
      gl_lds16(srcArr +                                                            \
                   (((size_t)(rowbase + (t >> 1)) * 16 + 2 * (ks) + (t & 1)) * 512) + \
                   lane * 8,                                                       \
               &stg[buf][(w * 8 + t) * 512]);                                      \
    }                                                                              \
  } while (0)

  f32x4 acc[3][2][2] = {};
  STAGE(0, 0);
  int cur = 0;
#pragma unroll
  for (int ks = 0; ks < 8; ++ks) {
    __syncthreads();
    if (ks < 7) STAGE(cur ^ 1, ks + 1);
#pragma unroll
    for (int kf = 0; kf < 2; ++kf) {
      half8 af[2], bq_[2], bk_[2], bv_[2];
#pragma unroll
      for (int i = 0; i < 2; ++i)
        af[i] = *(const half8*)(&stg[cur][((mh + i) * 2 + kf) * 512 + lane * 8]);
#pragma unroll
      for (int j = 0; j < 2; ++j) {
        bq_[j] = *(const half8*)(&stg[cur][(8 + (nh + j) * 2 + kf) * 512 + lane * 8]);
        bk_[j] = *(const half8*)(&stg[cur][(16 + (nh + j) * 2 + kf) * 512 + lane * 8]);
        bv_[j] = *(const half8*)(&stg[cur][(24 + (nh + j) * 2 + kf) * 512 + lane * 8]);
      }
#pragma unroll
      for (int i = 0; i < 2; ++i)
#pragma unroll
        for (int j = 0; j < 2; ++j) {
          acc[0][i][j] = __builtin_amdgcn_mfma_f32_16x16x32_f16(af[i], bq_[j], acc[0][i][j], 0, 0, 0);
          acc[1][i][j] = __builtin_amdgcn_mfma_f32_16x16x32_f16(af[i], bk_[j], acc[1][i][j], 0, 0, 0);
          acc[2][i][j] = __builtin_amdgcn_mfma_f32_16x16x32_f16(af[i], bv_[j], acc[2][i][j], 0, 0, 0);
        }
    }
    cur ^= 1;
  }
#undef STAGE

  const int mt = (w >> 1) * 32, nt = (w & 1) * 32;
#pragma unroll
  for (int z = 0; z < 3; ++z) {
    const float* bias = z == 0 ? bq : z == 1 ? bk : bv;
#pragma unroll
    for (int i = 0; i < 2; ++i)
#pragma unroll
      for (int j = 0; j < 2; ++j) {
        int col = bn + nt + j * 16 + lo;
        int h = col >> 6, d = col & 63;
        float bb = bias[col];
#pragma unroll
        for (int r = 0; r < 4; ++r) {
          int row = bm + mt + i * 16 + quad * 4 + r;
          int b = row >> 9, is = row & 511;
          int bh = b * Hh + h;
          unsigned short val = f2h(acc[z][i][j][r] + bb);
          if (z == 0) {
            Qb[((size_t)bh * Nseq + is) * 64 + d] = val;
          } else if (z == 1) {
            int jt = is >> 4, kf2 = d >> 5, l = ((d >> 3) & 3) * 16 + (is & 15), e = d & 7;
            KF[(((size_t)bh * 32 + jt) * 2 + kf2) * 512 + l * 8 + e] = val;
          } else {
            int dt = d >> 4, ks = is >> 5, l = ((is >> 3) & 3) * 16 + (d & 15), e = is & 7;
            VF[(((size_t)bh * 4 + dt) * 16 + ks) * 512 + l * 8 + e] = val;
          }
        }
      }
  }
}

// ---------------------------------------------------------------------------
// attn_fused v3: direct global->VGPR K/V/Pv + in-place skewed P rewrite.
// UNCHANGED from round 3 (known ~24us).
// ---------------------------------------------------------------------------
__global__ __launch_bounds__(256, 4) void attn_fused(
    const unsigned short* __restrict__ Qb,
    const unsigned short* __restrict__ KF,
    const unsigned short* __restrict__ VF,
    const float* __restrict__ Pkt,
    const unsigned short* __restrict__ PvF2,
    unsigned short* __restrict__ AwF) {
  const int flat = blockIdx.x;
  const int h = flat & 7;
  const int grp = flat >> 3;
  const int b = grp >> 4;
  const int p = grp & 15;
  const int itA = (p >> 1) * 4 + (p & 1);  // pairs {it, it+2}
  const int i0A = itA * 16;
  const int bh = b * Hh + h;
  const int tid = threadIdx.x, w = tid >> 6, lane = tid & 63;
  const int lo = lane & 15, quad = lane >> 4;

  __shared__ __align__(16) unsigned short pstA[16 * STR + 512];
  __shared__ __align__(16) unsigned short pstB[16 * STR + 512];
  __shared__ float pk_lds[560];
  __shared__ float redm[128];
  __shared__ float redl[128];

  const int TB = 464 - i0A;

  int4 z4; z4.x = z4.y = z4.z = z4.w = 0;
  for (int c = tid; c < (16 * STR + 512) / 8; c += 256) {
    ((int4*)pstA)[c] = z4;
    ((int4*)pstB)[c] = z4;
  }
  for (int c = tid; c < 140; c += 256)
    *(float4*)(pk_lds + c * 4) = *(const float4*)(Pkt + (size_t)h * 1040 + TB + c * 4);

  const unsigned short* qA = Qb + ((size_t)bh * Nseq + i0A + lo) * 64;
  const unsigned short* qB = Qb + ((size_t)bh * Nseq + i0A + 32 + lo) * 64;
  half8 qa0 = *(const half8*)(qA + quad * 8);
  half8 qa1 = *(const half8*)(qA + 32 + quad * 8);
  half8 qb0 = *(const half8*)(qB + quad * 8);
  half8 qb1 = *(const half8*)(qB + 32 + quad * 8);

  const unsigned short* KFb = KF + ((size_t)bh * 64 + (size_t)w * 16) * 512 + lane * 8;
  const unsigned short* VFb = VF + ((size_t)bh * 4 + w) * 16 * 512 + lane * 8;
  const int aP = (TB >> 4) & 1, gtB = TB >> 5;
  const unsigned short* PFb =
      PvF2 + ((((size_t)aP * Hh + h) * 4 + w) * 32 + gtB) * 512 + lane * 8;

  __syncthreads();  // B1

  float svA[8][4], svB[8][4];
  float mA[4] = {-1e30f, -1e30f, -1e30f, -1e30f};
  float mB[4] = {-1e30f, -1e30f, -1e30f, -1e30f};
#pragma unroll
  for (int g = 0; g < 8; ++g) {
    half8 k0 = *(const half8*)(KFb + (size_t)(2 * g + 0) * 512);
    half8 k1 = *(const half8*)(KFb + (size_t)(2 * g + 1) * 512);
    f32x4 cA = {0.f, 0.f, 0.f, 0.f};
    f32x4 cB = {0.f, 0.f, 0.f, 0.f};
    cA = __builtin_amdgcn_mfma_f32_16x16x32_f16(qa0, k0, cA, 0, 0, 0);
    cA = __builtin_amdgcn_mfma_f32_16x16x32_f16(qa1, k1, cA, 0, 0, 0);
    cB = __builtin_amdgcn_mfma_f32_16x16x32_f16(qb0, k0, cB, 0, 0, 0);
    cB = __builtin_amdgcn_mfma_f32_16x16x32_f16(qb1, k1, cB, 0, 0, 0);
    int j = w * 128 + g * 16 + lo;
#pragma unroll
    for (int r = 0; r < 4; ++r) {
      int rl = quad * 4 + r;
      int idx = j - rl + 15;
      float vA = (cA[r] + pk_lds[idx + 32]) * 0.125f;
      float vB = (cB[r] + pk_lds[idx]) * 0.125f;
      svA[g][r] = vA; svB[g][r] = vB;
      mA[r] = fmaxf(mA[r], vA);
      mB[r] = fmaxf(mB[r], vB);
    }
  }

#pragma unroll
  for (int m = 1; m <= 8; m <<= 1)
#pragma unroll
    for (int r = 0; r < 4; ++r) {
      mA[r] = fmaxf(mA[r], __shfl_xor(mA[r], m));
      mB[r] = fmaxf(mB[r], __shfl_xor(mB[r], m));
    }
  if (lo == 0)
#pragma unroll
    for (int r = 0; r < 4; ++r) {
      redm[(0 * 4 + w) * 16 + quad * 4 + r] = mA[r];
      redm[(1 * 4 + w) * 16 + quad * 4 + r] = mB[r];
    }
  __syncthreads();  // B2
  float mfA[4], mfB[4];
#pragma unroll
  for (int r = 0; r < 4; ++r) {
    int rl = quad * 4 + r;
    mfA[r] = fmaxf(fmaxf(redm[rl], redm[16 + rl]), fmaxf(redm[32 + rl], redm[48 + rl]));
    mfB[r] = fmaxf(fmaxf(redm[64 + rl], redm[80 + rl]), fmaxf(redm[96 + rl], redm[112 + rl]));
  }
  float lA[4] = {0.f, 0.f, 0.f, 0.f}, lB[4] = {0.f, 0.f, 0.f, 0.f};
  unsigned int svp[8][4];  // packed fp16 exp values: lo=A, hi=B
#pragma unroll
  for (int s = 0; s < 8; ++s)
#pragma unroll
    for (int r = 0; r < 4; ++r) {
      float eA = __expf(svA[s][r] - mfA[r]);
      float eB = __expf(svB[s][r] - mfB[r]);
      lA[r] += eA; lB[r] += eB;
      svp[s][r] = (unsigned int)f2h(eA) | ((unsigned int)f2h(eB) << 16);
    }
#pragma unroll
  for (int m = 1; m <= 8; m <<= 1)
#pragma unroll
    for (int r = 0; r < 4; ++r) {
      lA[r] += __shfl_xor(lA[r], m);
      lB[r] += __shfl_xor(lB[r], m);
    }
  if (lo == 0)
#pragma unroll
    for (int r = 0; r < 4; ++r) {
      redl[(0 * 4 + w) * 16 + quad * 4 + r] = lA[r];
      redl[(1 * 4 + w) * 16 + quad * 4 + r] = lB[r];
    }
  __syncthreads();  // B3
  float liA[4], liB[4];
#pragma unroll
  for (int r = 0; r < 4; ++r) {
    int rl = quad * 4 + r;
    liA[r] = 1.f / (redl[rl] + redl[16 + rl] + redl[32 + rl] + redl[48 + rl]);
    liB[r] = 1.f / (redl[64 + rl] + redl[80 + rl] + redl[96 + rl] + redl[112 + rl]);
#pragma unroll
    for (int s = 0; s < 8; ++s) {
      int j = w * 128 + s * 16 + lo;
      pstA[rl * STR + 16 + j] = (unsigned short)svp[s][r];
      pstB[rl * STR + 16 + j] = (unsigned short)(svp[s][r] >> 16);
    }
  }
  __syncthreads();  // B4

  f32x4 oVA = {0.f, 0.f, 0.f, 0.f}, oVB = {0.f, 0.f, 0.f, 0.f};
#pragma unroll
  for (int g = 0; g < 8; ++g) {
    half8 v0 = *(const half8*)(VFb + (size_t)(2 * g + 0) * 512);
    half8 v1 = *(const half8*)(VFb + (size_t)(2 * g + 1) * 512);
#pragma unroll
    for (int c = 0; c < 2; ++c) {
      int ks = 2 * g + c;
      half8 vv = c ? v1 : v0;
      half8 pA = *(const half8*)(&pstA[lo * STR + 16 + ks * 32 + quad * 8]);
      half8 pB = *(const half8*)(&pstB[lo * STR + 16 + ks * 32 + quad * 8]);
      oVA = __builtin_amdgcn_mfma_f32_16x16x32_f16(pA, vv, oVA, 0, 0, 0);
      oVB = __builtin_amdgcn_mfma_f32_16x16x32_f16(pB, vv, oVB, 0, 0, 0);
    }
  }
  __syncthreads();  // B5

#pragma unroll
  for (int r = 0; r < 4; ++r) {
    int rl = quad * 4 + r;
#pragma unroll
    for (int s = 0; s < 8; ++s) {
      int j = w * 128 + s * 16 + lo;
      int x = j - rl + 15;
      unsigned int pv = svp[s][r];
      if (w == 3 && s == 7) {
        int addr = (x < 512) ? (rl * STR + x) : (16 * STR + rl * 32 + (x - 512));
        pstA[addr] = (unsigned short)pv;
        pstB[addr] = (unsigned short)(pv >> 16);
      } else {
        pstA[rl * STR + x] = (unsigned short)pv;
        pstB[rl * STR + x] = (unsigned short)(pv >> 16);
      }
    }
  }
  __syncthreads();  // B6

  f32x4 oPA = {0.f, 0.f, 0.f, 0.f}, oPB = {0.f, 0.f, 0.f, 0.f};
#pragma unroll
  for (int g = 0; g < 9; ++g) {
    half8 p0 = *(const half8*)(PFb + (size_t)(2 * g + 0) * 512);
    half8 p1 = *(const half8*)(PFb + (size_t)(2 * g + 1) * 512);
#pragma unroll
    for (int c = 0; c < 2; ++c) {
      int cg = 2 * g + c;
      half8 pvf = c ? p1 : p0;
      if (cg < 17) {
        const unsigned short* src = (cg < 16)
            ? &pstB[lo * STR + cg * 32 + quad * 8]
            : &pstB[16 * STR + lo * 32 + quad * 8];
        oPB = __builtin_amdgcn_mfma_f32_16x16x32_f16(*(const half8*)src, pvf, oPB, 0, 0, 0);
      }
      if (cg >= 1) {
        int ksA = cg - 1;
        const unsigned short* src = (ksA < 16)
            ? &pstA[lo * STR + ksA * 32 + quad * 8]
            : &pstA[16 * STR + lo * 32 + quad * 8];
        oPA = __builtin_amdgcn_mfma_f32_16x16x32_f16(*(const half8*)src, pvf, oPA, 0, 0, 0);
      }
    }
  }

  const int kf = h * 2 + (w >> 1);
  const int lhi = ((w & 1) * 2 + (lo >> 3)) * 16;
#pragma unroll
  for (int t = 0; t < 2; ++t) {
    int mc = b * 32 + itA + t * 2;
#pragma unroll
    for (int r = 0; r < 4; ++r) {
      float ov = t ? (oVB[r] + oPB[r]) * liB[r] : (oVA[r] + oPA[r]) * liA[r];
      size_t fl = (((size_t)mc * 16 + kf) * 64 + lhi + quad * 4 + r) * 8 + (lo & 7);
      AwF[fl] = f2h(ov);
    }
  }
}

// ---------------------------------------------------------------------------
// gemm_final: single-term fp16 MFMA, BK=64 staged. out = AwF @ WoF + bo.
// ---------------------------------------------------------------------------
__global__ __launch_bounds__(256, 2) void gemm_final(const unsigned short* __restrict__ AF,
                                                     const unsigned short* __restrict__ BF,
                                                     const float* __restrict__ bo,
                                                     float* __restrict__ out) {
  const int flat = blockIdx.x & 511;  // clone mapping (diagnostic)
  const int xcd = flat & 7, g = flat >> 3;
  const int by = xcd * 8 + (g & 7), bx = g >> 3;
  const int bm = by * 64, bn = bx * 64;
  const int mc0 = bm >> 4, nc0 = bn >> 4;
  const int tid = threadIdx.x, w = tid >> 6, lane = tid & 63;
  const int lo = lane & 15, quad = lane >> 4;
  const int mh = (w >> 1) * 2, nh = (w & 1) * 2;

  __shared__ __align__(16) unsigned short stg[2][16 * 512];

  const unsigned short* srcArr = (w < 2) ? AF : BF;
  const int rowbase = ((w < 2) ? mc0 : nc0) + (w & 1) * 2;

#define STAGE2(buf, ks)                                                            \
  do {                                                                             \
    _Pragma("unroll") for (int t = 0; t < 4; ++t) {                                \
      gl_lds16(srcArr +                                                            \
                   (((size_t)(rowbase + (t >> 1)) * 16 + 2 * (ks) + (t & 1)) * 512) + \
                   lane * 8,                                                       \
               &stg[buf][(w * 4 + t) * 512]);                                      \
    }                                                                              \
  } while (0)

  f32x4 acc[2][2] = {};
  STAGE2(0, 0);
  int cur = 0;
#pragma unroll
  for (int ks = 0; ks < 8; ++ks) {
    __syncthreads();
    if (ks < 7) STAGE2(cur ^ 1, ks + 1);
#pragma unroll
    for (int kf = 0; kf < 2; ++kf) {
      half8 af[2], bf[2];
#pragma unroll
      for (int i = 0; i < 2; ++i)
        af[i] = *(const half8*)(&stg[cur][((mh + i) * 2 + kf) * 512 + lane * 8]);
#pragma unroll
      for (int j = 0; j < 2; ++j)
        bf[j] = *(const half8*)(&stg[cur][(8 + (nh + j) * 2 + kf) * 512 + lane * 8]);
#pragma unroll
      for (int i = 0; i < 2; ++i)
#pragma unroll
        for (int j = 0; j < 2; ++j)
          acc[i][j] = __builtin_amdgcn_mfma_f32_16x16x32_f16(af[i], bf[j], acc[i][j], 0, 0, 0);
    }
    cur ^= 1;
  }
#undef STAGE2

  const int mt = (w >> 1) * 32, nt = (w & 1) * 32;
#pragma unroll
  for (int i = 0; i < 2; ++i)
#pragma unroll
    for (int j = 0; j < 2; ++j) {
      int col = bn + nt + j * 16 + lo;
      float bb = bo[col];
#pragma unroll
      for (int r = 0; r < 4; ++r) {
        int row = bm + mt + i * 16 + quad * 4 + r;
        out[(size_t)row * DM + col] = acc[i][j][r] + bb;
      }
    }
}

// ---------------------------------------------------------------------------
extern "C" void kernel_launch(void* const* d_in, const int* in_sizes, int n_in,
                              void* d_out, int out_size, void* d_ws, size_t ws_size,
                              hipStream_t stream) {
  const float* X  = (const float*)d_in[0];
  const float* Wq = (const float*)d_in[1];
  const float* bq = (const float*)d_in[2];
  const float* Wk = (const float*)d_in[3];
  const float* bk = (const float*)d_in[4];
  const float* Wv = (const float*)d_in[5];
  const float* bv = (const float*)d_in[6];
  const float* Wo = (const float*)d_in[7];
  const float* bo = (const float*)d_in[8];
  const float* Pk = (const float*)d_in[9];
  const float* Pv = (const float*)d_in[10];
  float* out = (float*)d_out;

  char* p = (char*)d_ws;
  const size_t szX    = (size_t)Bc * Nseq * DM * 2;        // 4 MB
  const size_t szW    = (size_t)DM * DM * 2;               // 512 KB
  const size_t szPkt  = (size_t)Hh * 1040 * 4;
  const size_t szPvF2 = (size_t)2 * Hh * 4 * 32 * 512 * 2; // 2 MB
  const size_t szQKV  = (size_t)Bc * Hh * Nseq * 64 * 2;   // 4 MB
  unsigned short* XbF = (unsigned short*)p; p += szX;
  unsigned short* WqF = (unsigned short*)p; p += szW;
  unsigned short* WkF = (unsigned short*)p; p += szW;
  unsigned short* WvF = (unsigned short*)p; p += szW;
  unsigned short* WoF = (unsigned short*)p; p += szW;
  float*          Pkt = (float*)p;          p += (szPkt + 255) & ~(size_t)255;
  unsigned short* PvF2 = (unsigned short*)p; p += szPvF2;
  unsigned short* Qb  = (unsigned short*)p; p += szQKV;
  unsigned short* KF  = (unsigned short*)p; p += szQKV;
  unsigned short* VF  = (unsigned short*)p; p += szQKV;
  unsigned short* AwF = (unsigned short*)p; p += szX;

  dim3 blk(256);
  // DIAGNOSTIC multipliers: prep x4, qkv x4, final x6 (idempotent clones)
  prep_all<<<dim3(2216 * 4), blk, 0, stream>>>(X, Wq, Wk, Wv, Wo, Pk, Pv,
                                               XbF, WqF, WkF, WvF, WoF, Pkt, PvF2);
  gemm_qkv<<<dim3(512 * 4), blk, 0, stream>>>(XbF, WqF, WkF, WvF, bq, bk, bv, Qb, KF, VF);
  attn_fused<<<dim3(1024), blk, 0, stream>>>(Qb, KF, VF, Pkt, PvF2, AwF);
  gemm_final<<<dim3(512 * 6), blk, 0, stream>>>(AwF, WoF, bo, out);
}

// Round 5
// 133.236 us; speedup vs baseline: 1.3182x; 1.3182x over previous
//
#include <hip/hip_runtime.h>
#include <math.h>

#define Bc 8
#define Nseq 512
#define DM 512
#define Hh 8
#define NUMREL 1023
#define ZOFF 511   // NUMREL/2
#define STR 552    // pstrip row stride (shorts)

typedef _Float16 half8 __attribute__((ext_vector_type(8)));
typedef float f32x4 __attribute__((ext_vector_type(4)));

__device__ __forceinline__ unsigned short f2h(float f) {
  _Float16 h = (_Float16)f;  // v_cvt_f16_f32, RNE
  return __builtin_bit_cast(unsigned short, h);
}

typedef __attribute__((address_space(3))) unsigned int as3_uint;
typedef __attribute__((address_space(1))) const unsigned int as1_uint;
__device__ __forceinline__ void gl_lds16(const void* g, void* l) {
  __builtin_amdgcn_global_load_lds((as1_uint*)g, (as3_uint*)l, 16, 0, 0);
}

// ---------------------------------------------------------------------------
// prep_all: bid [0,1024) X->XbF (A-frag-major fp16); [1024,2048) W->WqF/WkF/
// WvF/WoF (B-frag-major fp16); [2048,2088) Pk->Pkt fp32; [2088,2216) Pv->PvF2.
// ---------------------------------------------------------------------------
__global__ __launch_bounds__(256) void prep_all(
    const float* __restrict__ X, const float* __restrict__ Wq,
    const float* __restrict__ Wk, const float* __restrict__ Wv,
    const float* __restrict__ Wo, const float* __restrict__ Pk,
    const float* __restrict__ Pv,
    unsigned short* __restrict__ XbF, unsigned short* __restrict__ WqF,
    unsigned short* __restrict__ WkF, unsigned short* __restrict__ WvF,
    unsigned short* __restrict__ WoF,
    float* __restrict__ Pkt, unsigned short* __restrict__ PvF2) {
  __shared__ float tbuf[5120];
  const int bid = blockIdx.x;
  const int tid = threadIdx.x;

  if (bid < 1024) {
    const int w = tid >> 6, lane = tid & 63;
    const int r = bid * 4 + w;
    const float* src = X + (size_t)r * DM + lane * 8;
    float4 a = *(const float4*)src;
    float4 b = *(const float4*)(src + 4);
    ushort4 o0, o1;
    o0.x = f2h(a.x); o0.y = f2h(a.y); o0.z = f2h(a.z); o0.w = f2h(a.w);
    o1.x = f2h(b.x); o1.y = f2h(b.y); o1.z = f2h(b.z); o1.w = f2h(b.w);
    const int mc = r >> 4, kf = lane >> 2, l = (lane & 3) * 16 + (r & 15);
    size_t flat = (((size_t)mc * 16 + kf) * 64 + l) * 8;
    *(ushort4*)(XbF + flat) = o0;
    *(ushort4*)(XbF + flat + 4) = o1;
  } else if (bid < 2048) {
    const int idx = bid - 1024;
    const int z = idx >> 8, r256 = idx & 255;
    const int bx = r256 & 15, by = r256 >> 4;
    const float* src = z == 0 ? Wq : z == 1 ? Wk : z == 2 ? Wv : Wo;
    unsigned short* dst = z == 0 ? WqF : z == 1 ? WkF : z == 2 ? WvF : WoF;
    const int k0 = by * 32, n0 = bx * 32;
#pragma unroll
    for (int u = 0; u < 4; ++u) {
      int i2 = u * 256 + tid, r = i2 >> 5, c = i2 & 31;
      tbuf[r * 33 + c] = src[(size_t)(k0 + r) * DM + n0 + c];
    }
    __syncthreads();
    const int ncl = tid >> 7, l = (tid >> 1) & 63, eh = tid & 1;
    const int nl = ncl * 16 + (l & 15);
    const int klb = (l >> 4) * 8 + eh * 4;
    ushort4 o;
    o.x = f2h(tbuf[(klb + 0) * 33 + nl]);
    o.y = f2h(tbuf[(klb + 1) * 33 + nl]);
    o.z = f2h(tbuf[(klb + 2) * 33 + nl]);
    o.w = f2h(tbuf[(klb + 3) * 33 + nl]);
    size_t flat = (((size_t)((n0 >> 4) + ncl) * 16 + (k0 >> 5)) * 64 + l) * 8 + eh * 4;
    *(ushort4*)(dst + flat) = o;
  } else if (bid < 2088) {
    const int idx = bid - 2048;
    const int gx = idx % 5, h = idx / 5;
    const int g = gx * 256 + tid;
    if (g < 1040)
      Pkt[(size_t)h * 1040 + g] = (g < NUMREL) ? Pk[(size_t)g * Hh + h] : 0.f;
  } else {
    const int idx = bid - 2088;
    const int gx = idx & 15, h = idx >> 4;
    const int g0 = gx * 64;
#pragma unroll
    for (int u = 0; u < 20; ++u) {
      int i2 = u * 256 + tid, r = i2 >> 6, c = i2 & 63;
      int g = g0 + r;
      tbuf[r * 64 + c] = (g < NUMREL) ? Pv[(size_t)g * 512 + h * 64 + c] : 0.f;
    }
    __syncthreads();
#pragma unroll
    for (int av = 0; av < 2; ++av)
#pragma unroll
      for (int gtl = 0; gtl < 2; ++gtl) {
        int gt = (g0 >> 5) + gtl;
#pragma unroll
        for (int dt = 0; dt < 4; ++dt) {
          size_t base = ((((size_t)av * Hh + h) * 4 + dt) * 32 + gt) * 512;
          int i2 = tid * 2;
          int l = i2 >> 3, e = i2 & 7;
          int gr = av * 16 + gtl * 32 + (l >> 4) * 8 + e;
          int dcol = dt * 16 + (l & 15);
          ushort2 o;
          o.x = f2h(tbuf[gr * 64 + dcol]);
          o.y = f2h(tbuf[(gr + 1) * 64 + dcol]);
          *(ushort2*)(PvF2 + base + i2) = o;
        }
      }
  }
}

// ---------------------------------------------------------------------------
// gemm_qkv v2: BK=32 (was 64) -> stg 32 KB -> 4 blocks/CU (was 2). Same
// k-accumulation order (bitwise identical); 16 K-steps of 12 MFMA each.
// Slot layout per buffer: [0-3]=X rows, [4-7]=Wq, [8-11]=Wk, [12-15]=Wv.
// ---------------------------------------------------------------------------
__global__ __launch_bounds__(256, 4) void gemm_qkv(const unsigned short* __restrict__ XbF,
                                                   const unsigned short* __restrict__ WqF,
                                                   const unsigned short* __restrict__ WkF,
                                                   const unsigned short* __restrict__ WvF,
                                                   const float* __restrict__ bq,
                                                   const float* __restrict__ bk,
                                                   const float* __restrict__ bv,
                                                   unsigned short* __restrict__ Qb,
                                                   unsigned short* __restrict__ KF,
                                                   unsigned short* __restrict__ VF) {
  const int flat = blockIdx.x;
  const int xcd = flat & 7, g = flat >> 3;
  const int by = xcd * 8 + (g & 7), bx = g >> 3;
  const int bm = by * 64, bn = bx * 64;
  const int mc0 = bm >> 4, nc0 = bn >> 4;
  const int tid = threadIdx.x, w = tid >> 6, lane = tid & 63;
  const int lo = lane & 15, quad = lane >> 4;
  const int mh = (w >> 1) * 2, nh = (w & 1) * 2;

  __shared__ __align__(16) unsigned short stg[2][16 * 512];

  const unsigned short* srcArr = w == 0 ? XbF : w == 1 ? WqF : w == 2 ? WkF : WvF;
  const int rowbase = (w == 0) ? mc0 : nc0;

#define STAGE(buf, ks)                                                      \
  do {                                                                      \
    _Pragma("unroll") for (int t = 0; t < 4; ++t) {                         \
      gl_lds16(srcArr + (((size_t)(rowbase + t) * 16 + (ks)) * 512) +       \
                   lane * 8,                                                \
               &stg[buf][(w * 4 + t) * 512]);                               \
    }                                                                       \
  } while (0)

  f32x4 acc[3][2][2] = {};
  STAGE(0, 0);
  int cur = 0;
#pragma unroll
  for (int ks = 0; ks < 16; ++ks) {
    __syncthreads();
    if (ks < 15) STAGE(cur ^ 1, ks + 1);
    half8 af[2], bq_[2], bk_[2], bv_[2];
#pragma unroll
    for (int i = 0; i < 2; ++i)
      af[i] = *(const half8*)(&stg[cur][(mh + i) * 512 + lane * 8]);
#pragma unroll
    for (int j = 0; j < 2; ++j) {
      bq_[j] = *(const half8*)(&stg[cur][(4 + nh + j) * 512 + lane * 8]);
      bk_[j] = *(const half8*)(&stg[cur][(8 + nh + j) * 512 + lane * 8]);
      bv_[j] = *(const half8*)(&stg[cur][(12 + nh + j) * 512 + lane * 8]);
    }
#pragma unroll
    for (int i = 0; i < 2; ++i)
#pragma unroll
      for (int j = 0; j < 2; ++j) {
        acc[0][i][j] = __builtin_amdgcn_mfma_f32_16x16x32_f16(af[i], bq_[j], acc[0][i][j], 0, 0, 0);
        acc[1][i][j] = __builtin_amdgcn_mfma_f32_16x16x32_f16(af[i], bk_[j], acc[1][i][j], 0, 0, 0);
        acc[2][i][j] = __builtin_amdgcn_mfma_f32_16x16x32_f16(af[i], bv_[j], acc[2][i][j], 0, 0, 0);
      }
    cur ^= 1;
  }
#undef STAGE

  const int mt = (w >> 1) * 32, nt = (w & 1) * 32;
#pragma unroll
  for (int z = 0; z < 3; ++z) {
    const float* bias = z == 0 ? bq : z == 1 ? bk : bv;
#pragma unroll
    for (int i = 0; i < 2; ++i)
#pragma unroll
      for (int j = 0; j < 2; ++j) {
        int col = bn + nt + j * 16 + lo;
        int h = col >> 6, d = col & 63;
        float bb = bias[col];
#pragma unroll
        for (int r = 0; r < 4; ++r) {
          int row = bm + mt + i * 16 + quad * 4 + r;
          int b = row >> 9, is = row & 511;
          int bh = b * Hh + h;
          unsigned short val = f2h(acc[z][i][j][r] + bb);
          if (z == 0) {
            Qb[((size_t)bh * Nseq + is) * 64 + d] = val;
          } else if (z == 1) {
            int jt = is >> 4, kf2 = d >> 5, l = ((d >> 3) & 3) * 16 + (is & 15), e = d & 7;
            KF[(((size_t)bh * 32 + jt) * 2 + kf2) * 512 + l * 8 + e] = val;
          } else {
            int dt = d >> 4, ks = is >> 5, l = ((is >> 3) & 3) * 16 + (d & 15), e = is & 7;
            VF[(((size_t)bh * 4 + dt) * 16 + ks) * 512 + l * 8 + e] = val;
          }
        }
      }
  }
}

// ---------------------------------------------------------------------------
// attn_fused v4: v3 + minimal zero-init (only read-but-unwritten pad: 16-short
// row heads + 512-short tail per strip; phase2 reads [16,528) all written,
// phase2b reads x in [0,511] with x<15-row covered by head zeros) + T5
// setprio(1) around MFMA clusters (independent blocks -> role diversity).
// ---------------------------------------------------------------------------
__global__ __launch_bounds__(256, 4) void attn_fused(
    const unsigned short* __restrict__ Qb,
    const unsigned short* __restrict__ KF,
    const unsigned short* __restrict__ VF,
    const float* __restrict__ Pkt,
    const unsigned short* __restrict__ PvF2,
    unsigned short* __restrict__ AwF) {
  const int flat = blockIdx.x;
  const int h = flat & 7;
  const int grp = flat >> 3;
  const int b = grp >> 4;
  const int p = grp & 15;
  const int itA = (p >> 1) * 4 + (p & 1);  // pairs {it, it+2}
  const int i0A = itA * 16;
  const int bh = b * Hh + h;
  const int tid = threadIdx.x, w = tid >> 6, lane = tid & 63;
  const int lo = lane & 15, quad = lane >> 4;

  __shared__ __align__(16) unsigned short pstA[16 * STR + 512];
  __shared__ __align__(16) unsigned short pstB[16 * STR + 512];
  __shared__ float pk_lds[560];
  __shared__ float redm[128];
  __shared__ float redl[128];

  const int TB = 464 - i0A;

  // minimal zero-init: 96 int4 per strip = 32 row-heads (16 rows x 16 shorts)
  // + 64 tail (512 shorts). All 16B-aligned (STR*2 = 1104 = 69*16).
  {
    int4 z4; z4.x = z4.y = z4.z = z4.w = 0;
    int c = tid;
    if (c < 96) {
      int addr = (c < 32) ? ((c >> 1) * STR + (c & 1) * 8)
                          : (16 * STR + (c - 32) * 8);
      *(int4*)(pstA + addr) = z4;
    } else if (c < 192) {
      int c2 = c - 96;
      int addr = (c2 < 32) ? ((c2 >> 1) * STR + (c2 & 1) * 8)
                           : (16 * STR + (c2 - 32) * 8);
      *(int4*)(pstB + addr) = z4;
    }
  }
  for (int c = tid; c < 140; c += 256)
    *(float4*)(pk_lds + c * 4) = *(const float4*)(Pkt + (size_t)h * 1040 + TB + c * 4);

  const unsigned short* qA = Qb + ((size_t)bh * Nseq + i0A + lo) * 64;
  const unsigned short* qB = Qb + ((size_t)bh * Nseq + i0A + 32 + lo) * 64;
  half8 qa0 = *(const half8*)(qA + quad * 8);
  half8 qa1 = *(const half8*)(qA + 32 + quad * 8);
  half8 qb0 = *(const half8*)(qB + quad * 8);
  half8 qb1 = *(const half8*)(qB + 32 + quad * 8);

  const unsigned short* KFb = KF + ((size_t)bh * 64 + (size_t)w * 16) * 512 + lane * 8;
  const unsigned short* VFb = VF + ((size_t)bh * 4 + w) * 16 * 512 + lane * 8;
  const int aP = (TB >> 4) & 1, gtB = TB >> 5;
  const unsigned short* PFb =
      PvF2 + ((((size_t)aP * Hh + h) * 4 + w) * 32 + gtB) * 512 + lane * 8;

  __syncthreads();  // B1

  // ---------------- Phase 1: scores ----------------
  float svA[8][4], svB[8][4];
  float mA[4] = {-1e30f, -1e30f, -1e30f, -1e30f};
  float mB[4] = {-1e30f, -1e30f, -1e30f, -1e30f};
#pragma unroll
  for (int g = 0; g < 8; ++g) {
    half8 k0 = *(const half8*)(KFb + (size_t)(2 * g + 0) * 512);
    half8 k1 = *(const half8*)(KFb + (size_t)(2 * g + 1) * 512);
    f32x4 cA = {0.f, 0.f, 0.f, 0.f};
    f32x4 cB = {0.f, 0.f, 0.f, 0.f};
    __builtin_amdgcn_s_setprio(1);
    cA = __builtin_amdgcn_mfma_f32_16x16x32_f16(qa0, k0, cA, 0, 0, 0);
    cA = __builtin_amdgcn_mfma_f32_16x16x32_f16(qa1, k1, cA, 0, 0, 0);
    cB = __builtin_amdgcn_mfma_f32_16x16x32_f16(qb0, k0, cB, 0, 0, 0);
    cB = __builtin_amdgcn_mfma_f32_16x16x32_f16(qb1, k1, cB, 0, 0, 0);
    __builtin_amdgcn_s_setprio(0);
    int j = w * 128 + g * 16 + lo;
#pragma unroll
    for (int r = 0; r < 4; ++r) {
      int rl = quad * 4 + r;
      int idx = j - rl + 15;
      float vA = (cA[r] + pk_lds[idx + 32]) * 0.125f;
      float vB = (cB[r] + pk_lds[idx]) * 0.125f;
      svA[g][r] = vA; svB[g][r] = vB;
      mA[r] = fmaxf(mA[r], vA);
      mB[r] = fmaxf(mB[r], vB);
    }
  }

  // ---------------- softmax x2 ----------------
#pragma unroll
  for (int m = 1; m <= 8; m <<= 1)
#pragma unroll
    for (int r = 0; r < 4; ++r) {
      mA[r] = fmaxf(mA[r], __shfl_xor(mA[r], m));
      mB[r] = fmaxf(mB[r], __shfl_xor(mB[r], m));
    }
  if (lo == 0)
#pragma unroll
    for (int r = 0; r < 4; ++r) {
      redm[(0 * 4 + w) * 16 + quad * 4 + r] = mA[r];
      redm[(1 * 4 + w) * 16 + quad * 4 + r] = mB[r];
    }
  __syncthreads();  // B2
  float mfA[4], mfB[4];
#pragma unroll
  for (int r = 0; r < 4; ++r) {
    int rl = quad * 4 + r;
    mfA[r] = fmaxf(fmaxf(redm[rl], redm[16 + rl]), fmaxf(redm[32 + rl], redm[48 + rl]));
    mfB[r] = fmaxf(fmaxf(redm[64 + rl], redm[80 + rl]), fmaxf(redm[96 + rl], redm[112 + rl]));
  }
  float lA[4] = {0.f, 0.f, 0.f, 0.f}, lB[4] = {0.f, 0.f, 0.f, 0.f};
  unsigned int svp[8][4];  // packed fp16 exp values: lo=A, hi=B
#pragma unroll
  for (int s = 0; s < 8; ++s)
#pragma unroll
    for (int r = 0; r < 4; ++r) {
      float eA = __expf(svA[s][r] - mfA[r]);
      float eB = __expf(svB[s][r] - mfB[r]);
      lA[r] += eA; lB[r] += eB;
      svp[s][r] = (unsigned int)f2h(eA) | ((unsigned int)f2h(eB) << 16);
    }
#pragma unroll
  for (int m = 1; m <= 8; m <<= 1)
#pragma unroll
    for (int r = 0; r < 4; ++r) {
      lA[r] += __shfl_xor(lA[r], m);
      lB[r] += __shfl_xor(lB[r], m);
    }
  if (lo == 0)
#pragma unroll
    for (int r = 0; r < 4; ++r) {
      redl[(0 * 4 + w) * 16 + quad * 4 + r] = lA[r];
      redl[(1 * 4 + w) * 16 + quad * 4 + r] = lB[r];
    }
  __syncthreads();  // B3
  float liA[4], liB[4];
#pragma unroll
  for (int r = 0; r < 4; ++r) {
    int rl = quad * 4 + r;
    liA[r] = 1.f / (redl[rl] + redl[16 + rl] + redl[32 + rl] + redl[48 + rl]);
    liB[r] = 1.f / (redl[64 + rl] + redl[80 + rl] + redl[96 + rl] + redl[112 + rl]);
#pragma unroll
    for (int s = 0; s < 8; ++s) {
      int j = w * 128 + s * 16 + lo;
      pstA[rl * STR + 16 + j] = (unsigned short)svp[s][r];
      pstB[rl * STR + 16 + j] = (unsigned short)(svp[s][r] >> 16);
    }
  }
  __syncthreads();  // B4

  // ---------------- Phase 2: P@V ----------------
  f32x4 oVA = {0.f, 0.f, 0.f, 0.f}, oVB = {0.f, 0.f, 0.f, 0.f};
#pragma unroll
  for (int g = 0; g < 8; ++g) {
    half8 v0 = *(const half8*)(VFb + (size_t)(2 * g + 0) * 512);
    half8 v1 = *(const half8*)(VFb + (size_t)(2 * g + 1) * 512);
#pragma unroll
    for (int c = 0; c < 2; ++c) {
      int ks = 2 * g + c;
      half8 vv = c ? v1 : v0;
      half8 pA = *(const half8*)(&pstA[lo * STR + 16 + ks * 32 + quad * 8]);
      half8 pB = *(const half8*)(&pstB[lo * STR + 16 + ks * 32 + quad * 8]);
      __builtin_amdgcn_s_setprio(1);
      oVA = __builtin_amdgcn_mfma_f32_16x16x32_f16(pA, vv, oVA, 0, 0, 0);
      oVB = __builtin_amdgcn_mfma_f32_16x16x32_f16(pB, vv, oVB, 0, 0, 0);
      __builtin_amdgcn_s_setprio(0);
    }
  }
  __syncthreads();  // B5

  // ---------------- in-place skewed rewrite ----------------
#pragma unroll
  for (int r = 0; r < 4; ++r) {
    int rl = quad * 4 + r;
#pragma unroll
    for (int s = 0; s < 8; ++s) {
      int j = w * 128 + s * 16 + lo;
      int x = j - rl + 15;
      unsigned int pv = svp[s][r];
      if (w == 3 && s == 7) {
        int addr = (x < 512) ? (rl * STR + x) : (16 * STR + rl * 32 + (x - 512));
        pstA[addr] = (unsigned short)pv;
        pstB[addr] = (unsigned short)(pv >> 16);
      } else {
        pstA[rl * STR + x] = (unsigned short)pv;
        pstB[rl * STR + x] = (unsigned short)(pv >> 16);
      }
    }
  }
  __syncthreads();  // B6

  // ---------------- Phase 2b: P'@Pv ----------------
  f32x4 oPA = {0.f, 0.f, 0.f, 0.f}, oPB = {0.f, 0.f, 0.f, 0.f};
#pragma unroll
  for (int g = 0; g < 9; ++g) {
    half8 p0 = *(const half8*)(PFb + (size_t)(2 * g + 0) * 512);
    half8 p1 = *(const half8*)(PFb + (size_t)(2 * g + 1) * 512);
#pragma unroll
    for (int c = 0; c < 2; ++c) {
      int cg = 2 * g + c;
      half8 pvf = c ? p1 : p0;
      if (cg < 17) {
        const unsigned short* src = (cg < 16)
            ? &pstB[lo * STR + cg * 32 + quad * 8]
            : &pstB[16 * STR + lo * 32 + quad * 8];
        half8 pb = *(const half8*)src;
        __builtin_amdgcn_s_setprio(1);
        oPB = __builtin_amdgcn_mfma_f32_16x16x32_f16(pb, pvf, oPB, 0, 0, 0);
        __builtin_amdgcn_s_setprio(0);
      }
      if (cg >= 1) {
        int ksA = cg - 1;
        const unsigned short* src = (ksA < 16)
            ? &pstA[lo * STR + ksA * 32 + quad * 8]
            : &pstA[16 * STR + lo * 32 + quad * 8];
        half8 pa = *(const half8*)src;
        __builtin_amdgcn_s_setprio(1);
        oPA = __builtin_amdgcn_mfma_f32_16x16x32_f16(pa, pvf, oPA, 0, 0, 0);
        __builtin_amdgcn_s_setprio(0);
      }
    }
  }

  // epilogue x2: single A-frag-major AwF, normalize here
  const int kf = h * 2 + (w >> 1);
  const int lhi = ((w & 1) * 2 + (lo >> 3)) * 16;
#pragma unroll
  for (int t = 0; t < 2; ++t) {
    int mc = b * 32 + itA + t * 2;
#pragma unroll
    for (int r = 0; r < 4; ++r) {
      float ov = t ? (oVB[r] + oPB[r]) * liB[r] : (oVA[r] + oPA[r]) * liA[r];
      size_t fl = (((size_t)mc * 16 + kf) * 64 + lhi + quad * 4 + r) * 8 + (lo & 7);
      AwF[fl] = f2h(ov);
    }
  }
}

// ---------------------------------------------------------------------------
// gemm_final: single-term fp16 MFMA, BK=64 staged. out = AwF @ WoF + bo.
// ---------------------------------------------------------------------------
__global__ __launch_bounds__(256, 2) void gemm_final(const unsigned short* __restrict__ AF,
                                                     const unsigned short* __restrict__ BF,
                                                     const float* __restrict__ bo,
                                                     float* __restrict__ out) {
  const int flat = blockIdx.x;
  const int xcd = flat & 7, g = flat >> 3;
  const int by = xcd * 8 + (g & 7), bx = g >> 3;
  const int bm = by * 64, bn = bx * 64;
  const int mc0 = bm >> 4, nc0 = bn >> 4;
  const int tid = threadIdx.x, w = tid >> 6, lane = tid & 63;
  const int lo = lane & 15, quad = lane >> 4;
  const int mh = (w >> 1) * 2, nh = (w & 1) * 2;

  __shared__ __align__(16) unsigned short stg[2][16 * 512];

  const unsigned short* srcArr = (w < 2) ? AF : BF;
  const int rowbase = ((w < 2) ? mc0 : nc0) + (w & 1) * 2;

#define STAGE2(buf, ks)                                                            \
  do {                                                                             \
    _Pragma("unroll") for (int t = 0; t < 4; ++t) {                                \
      gl_lds16(srcArr +                                                            \
                   (((size_t)(rowbase + (t >> 1)) * 16 + 2 * (ks) + (t & 1)) * 512) + \
                   lane * 8,                                                       \
               &stg[buf][(w * 4 + t) * 512]);                                      \
    }                                                                              \
  } while (0)

  f32x4 acc[2][2] = {};
  STAGE2(0, 0);
  int cur = 0;
#pragma unroll
  for (int ks = 0; ks < 8; ++ks) {
    __syncthreads();
    if (ks < 7) STAGE2(cur ^ 1, ks + 1);
#pragma unroll
    for (int kf = 0; kf < 2; ++kf) {
      half8 af[2], bf[2];
#pragma unroll
      for (int i = 0; i < 2; ++i)
        af[i] = *(const half8*)(&stg[cur][((mh + i) * 2 + kf) * 512 + lane * 8]);
#pragma unroll
      for (int j = 0; j < 2; ++j)
        bf[j] = *(const half8*)(&stg[cur][(8 + (nh + j) * 2 + kf) * 512 + lane * 8]);
#pragma unroll
      for (int i = 0; i < 2; ++i)
#pragma unroll
        for (int j = 0; j < 2; ++j)
          acc[i][j] = __builtin_amdgcn_mfma_f32_16x16x32_f16(af[i], bf[j], acc[i][j], 0, 0, 0);
    }
    cur ^= 1;
  }
#undef STAGE2

  const int mt = (w >> 1) * 32, nt = (w & 1) * 32;
#pragma unroll
  for (int i = 0; i < 2; ++i)
#pragma unroll
    for (int j = 0; j < 2; ++j) {
      int col = bn + nt + j * 16 + lo;
      float bb = bo[col];
#pragma unroll
      for (int r = 0; r < 4; ++r) {
        int row = bm + mt + i * 16 + quad * 4 + r;
        out[(size_t)row * DM + col] = acc[i][j][r] + bb;
      }
    }
}

// ---------------------------------------------------------------------------
extern "C" void kernel_launch(void* const* d_in, const int* in_sizes, int n_in,
                              void* d_out, int out_size, void* d_ws, size_t ws_size,
                              hipStream_t stream) {
  const float* X  = (const float*)d_in[0];
  const float* Wq = (const float*)d_in[1];
  const float* bq = (const float*)d_in[2];
  const float* Wk = (const float*)d_in[3];
  const float* bk = (const float*)d_in[4];
  const float* Wv = (const float*)d_in[5];
  const float* bv = (const float*)d_in[6];
  const float* Wo = (const float*)d_in[7];
  const float* bo = (const float*)d_in[8];
  const float* Pk = (const float*)d_in[9];
  const float* Pv = (const float*)d_in[10];
  float* out = (float*)d_out;

  char* p = (char*)d_ws;
  const size_t szX    = (size_t)Bc * Nseq * DM * 2;        // 4 MB
  const size_t szW    = (size_t)DM * DM * 2;               // 512 KB
  const size_t szPkt  = (size_t)Hh * 1040 * 4;
  const size_t szPvF2 = (size_t)2 * Hh * 4 * 32 * 512 * 2; // 2 MB
  const size_t szQKV  = (size_t)Bc * Hh * Nseq * 64 * 2;   // 4 MB
  unsigned short* XbF = (unsigned short*)p; p += szX;
  unsigned short* WqF = (unsigned short*)p; p += szW;
  unsigned short* WkF = (unsigned short*)p; p += szW;
  unsigned short* WvF = (unsigned short*)p; p += szW;
  unsigned short* WoF = (unsigned short*)p; p += szW;
  float*          Pkt = (float*)p;          p += (szPkt + 255) & ~(size_t)255;
  unsigned short* PvF2 = (unsigned short*)p; p += szPvF2;
  unsigned short* Qb  = (unsigned short*)p; p += szQKV;
  unsigned short* KF  = (unsigned short*)p; p += szQKV;
  unsigned short* VF  = (unsigned short*)p; p += szQKV;
  unsigned short* AwF = (unsigned short*)p; p += szX;

  dim3 blk(256);
  prep_all<<<dim3(2216), blk, 0, stream>>>(X, Wq, Wk, Wv, Wo, Pk, Pv,
                                           XbF, WqF, WkF, WvF, WoF, Pkt, PvF2);
  gemm_qkv<<<dim3(512), blk, 0, stream>>>(XbF, WqF, WkF, WvF, bq, bk, bv, Qb, KF, VF);
  attn_fused<<<dim3(1024), blk, 0, stream>>>(Qb, KF, VF, Pkt, PvF2, AwF);
  gemm_final<<<dim3(512), blk, 0, stream>>>(AwF, WoF, bo, out);
}

// Round 6
// 125.325 us; speedup vs baseline: 1.4014x; 1.0631x over previous
//
#include <hip/hip_runtime.h>
#include <math.h>

#define Bc 8
#define Nseq 512
#define DM 512
#define Hh 8
#define NUMREL 1023
#define ZOFF 511   // NUMREL/2
#define STR 552    // pstrip row stride (shorts)

typedef _Float16 half8 __attribute__((ext_vector_type(8)));
typedef float f32x4 __attribute__((ext_vector_type(4)));

__device__ __forceinline__ unsigned short f2h(float f) {
  _Float16 h = (_Float16)f;  // v_cvt_f16_f32, RNE
  return __builtin_bit_cast(unsigned short, h);
}

typedef __attribute__((address_space(3))) unsigned int as3_uint;
typedef __attribute__((address_space(1))) const unsigned int as1_uint;
__device__ __forceinline__ void gl_lds16(const void* g, void* l) {
  __builtin_amdgcn_global_load_lds((as1_uint*)g, (as3_uint*)l, 16, 0, 0);
}

// ---------------------------------------------------------------------------
// prep_all: bid [0,1024) X->XbF (A-frag-major fp16); [1024,2048) W->WqF/WkF/
// WvF/WoF (B-frag-major fp16); [2048,2088) Pk->Pkt fp32; [2088,2216) Pv->PvF2.
// ---------------------------------------------------------------------------
__global__ __launch_bounds__(256) void prep_all(
    const float* __restrict__ X, const float* __restrict__ Wq,
    const float* __restrict__ Wk, const float* __restrict__ Wv,
    const float* __restrict__ Wo, const float* __restrict__ Pk,
    const float* __restrict__ Pv,
    unsigned short* __restrict__ XbF, unsigned short* __restrict__ WqF,
    unsigned short* __restrict__ WkF, unsigned short* __restrict__ WvF,
    unsigned short* __restrict__ WoF,
    float* __restrict__ Pkt, unsigned short* __restrict__ PvF2) {
  __shared__ float tbuf[5120];
  const int bid = blockIdx.x;
  const int tid = threadIdx.x;

  if (bid < 1024) {
    const int w = tid >> 6, lane = tid & 63;
    const int r = bid * 4 + w;
    const float* src = X + (size_t)r * DM + lane * 8;
    float4 a = *(const float4*)src;
    float4 b = *(const float4*)(src + 4);
    ushort4 o0, o1;
    o0.x = f2h(a.x); o0.y = f2h(a.y); o0.z = f2h(a.z); o0.w = f2h(a.w);
    o1.x = f2h(b.x); o1.y = f2h(b.y); o1.z = f2h(b.z); o1.w = f2h(b.w);
    const int mc = r >> 4, kf = lane >> 2, l = (lane & 3) * 16 + (r & 15);
    size_t flat = (((size_t)mc * 16 + kf) * 64 + l) * 8;
    *(ushort4*)(XbF + flat) = o0;
    *(ushort4*)(XbF + flat + 4) = o1;
  } else if (bid < 2048) {
    const int idx = bid - 1024;
    const int z = idx >> 8, r256 = idx & 255;
    const int bx = r256 & 15, by = r256 >> 4;
    const float* src = z == 0 ? Wq : z == 1 ? Wk : z == 2 ? Wv : Wo;
    unsigned short* dst = z == 0 ? WqF : z == 1 ? WkF : z == 2 ? WvF : WoF;
    const int k0 = by * 32, n0 = bx * 32;
#pragma unroll
    for (int u = 0; u < 4; ++u) {
      int i2 = u * 256 + tid, r = i2 >> 5, c = i2 & 31;
      tbuf[r * 33 + c] = src[(size_t)(k0 + r) * DM + n0 + c];
    }
    __syncthreads();
    const int ncl = tid >> 7, l = (tid >> 1) & 63, eh = tid & 1;
    const int nl = ncl * 16 + (l & 15);
    const int klb = (l >> 4) * 8 + eh * 4;
    ushort4 o;
    o.x = f2h(tbuf[(klb + 0) * 33 + nl]);
    o.y = f2h(tbuf[(klb + 1) * 33 + nl]);
    o.z = f2h(tbuf[(klb + 2) * 33 + nl]);
    o.w = f2h(tbuf[(klb + 3) * 33 + nl]);
    size_t flat = (((size_t)((n0 >> 4) + ncl) * 16 + (k0 >> 5)) * 64 + l) * 8 + eh * 4;
    *(ushort4*)(dst + flat) = o;
  } else if (bid < 2088) {
    const int idx = bid - 2048;
    const int gx = idx % 5, h = idx / 5;
    const int g = gx * 256 + tid;
    if (g < 1040)
      Pkt[(size_t)h * 1040 + g] = (g < NUMREL) ? Pk[(size_t)g * Hh + h] : 0.f;
  } else {
    const int idx = bid - 2088;
    const int gx = idx & 15, h = idx >> 4;
    const int g0 = gx * 64;
#pragma unroll
    for (int u = 0; u < 20; ++u) {
      int i2 = u * 256 + tid, r = i2 >> 6, c = i2 & 63;
      int g = g0 + r;
      tbuf[r * 64 + c] = (g < NUMREL) ? Pv[(size_t)g * 512 + h * 64 + c] : 0.f;
    }
    __syncthreads();
#pragma unroll
    for (int av = 0; av < 2; ++av)
#pragma unroll
      for (int gtl = 0; gtl < 2; ++gtl) {
        int gt = (g0 >> 5) + gtl;
#pragma unroll
        for (int dt = 0; dt < 4; ++dt) {
          size_t base = ((((size_t)av * Hh + h) * 4 + dt) * 32 + gt) * 512;
          int i2 = tid * 2;
          int l = i2 >> 3, e = i2 & 7;
          int gr = av * 16 + gtl * 32 + (l >> 4) * 8 + e;
          int dcol = dt * 16 + (l & 15);
          ushort2 o;
          o.x = f2h(tbuf[gr * 64 + dcol]);
          o.y = f2h(tbuf[(gr + 1) * 64 + dcol]);
          *(ushort2*)(PvF2 + base + i2) = o;
        }
      }
  }
}

// ---------------------------------------------------------------------------
// gemm_qkv: z-fused fp16 MFMA, frag-major, BK=64 staged (R3 config — BK=32
// experiment reverted: doubling barrier-drain count netted <=0).
// ---------------------------------------------------------------------------
__global__ __launch_bounds__(256, 2) void gemm_qkv(const unsigned short* __restrict__ XbF,
                                                   const unsigned short* __restrict__ WqF,
                                                   const unsigned short* __restrict__ WkF,
                                                   const unsigned short* __restrict__ WvF,
                                                   const float* __restrict__ bq,
                                                   const float* __restrict__ bk,
                                                   const float* __restrict__ bv,
                                                   unsigned short* __restrict__ Qb,
                                                   unsigned short* __restrict__ KF,
                                                   unsigned short* __restrict__ VF) {
  const int flat = blockIdx.x;
  const int xcd = flat & 7, g = flat >> 3;
  const int by = xcd * 8 + (g & 7), bx = g >> 3;
  const int bm = by * 64, bn = bx * 64;
  const int mc0 = bm >> 4, nc0 = bn >> 4;
  const int tid = threadIdx.x, w = tid >> 6, lane = tid & 63;
  const int lo = lane & 15, quad = lane >> 4;
  const int mh = (w >> 1) * 2, nh = (w & 1) * 2;

  __shared__ __align__(16) unsigned short stg[2][32 * 512];

  const unsigned short* srcArr = w == 0 ? XbF : w == 1 ? WqF : w == 2 ? WkF : WvF;
  const int rowbase = (w == 0) ? mc0 : nc0;

#define STAGE(buf, ks)                                                             \
  do {                                                                             \
    _Pragma("unroll") for (int t = 0; t < 8; ++t) {                                \
      gl_lds16(srcArr +                                                            \
                   (((size_t)(rowbase + (t >> 1)) * 16 + 2 * (ks) + (t & 1)) * 512) + \
                   lane * 8,                                                       \
               &stg[buf][(w * 8 + t) * 512]);                                      \
    }                                                                              \
  } while (0)

  f32x4 acc[3][2][2] = {};
  STAGE(0, 0);
  int cur = 0;
#pragma unroll
  for (int ks = 0; ks < 8; ++ks) {
    __syncthreads();
    if (ks < 7) STAGE(cur ^ 1, ks + 1);
#pragma unroll
    for (int kf = 0; kf < 2; ++kf) {
      half8 af[2], bq_[2], bk_[2], bv_[2];
#pragma unroll
      for (int i = 0; i < 2; ++i)
        af[i] = *(const half8*)(&stg[cur][((mh + i) * 2 + kf) * 512 + lane * 8]);
#pragma unroll
      for (int j = 0; j < 2; ++j) {
        bq_[j] = *(const half8*)(&stg[cur][(8 + (nh + j) * 2 + kf) * 512 + lane * 8]);
        bk_[j] = *(const half8*)(&stg[cur][(16 + (nh + j) * 2 + kf) * 512 + lane * 8]);
        bv_[j] = *(const half8*)(&stg[cur][(24 + (nh + j) * 2 + kf) * 512 + lane * 8]);
      }
#pragma unroll
      for (int i = 0; i < 2; ++i)
#pragma unroll
        for (int j = 0; j < 2; ++j) {
          acc[0][i][j] = __builtin_amdgcn_mfma_f32_16x16x32_f16(af[i], bq_[j], acc[0][i][j], 0, 0, 0);
          acc[1][i][j] = __builtin_amdgcn_mfma_f32_16x16x32_f16(af[i], bk_[j], acc[1][i][j], 0, 0, 0);
          acc[2][i][j] = __builtin_amdgcn_mfma_f32_16x16x32_f16(af[i], bv_[j], acc[2][i][j], 0, 0, 0);
        }
    }
    cur ^= 1;
  }
#undef STAGE

  const int mt = (w >> 1) * 32, nt = (w & 1) * 32;
#pragma unroll
  for (int z = 0; z < 3; ++z) {
    const float* bias = z == 0 ? bq : z == 1 ? bk : bv;
#pragma unroll
    for (int i = 0; i < 2; ++i)
#pragma unroll
      for (int j = 0; j < 2; ++j) {
        int col = bn + nt + j * 16 + lo;
        int h = col >> 6, d = col & 63;
        float bb = bias[col];
#pragma unroll
        for (int r = 0; r < 4; ++r) {
          int row = bm + mt + i * 16 + quad * 4 + r;
          int b = row >> 9, is = row & 511;
          int bh = b * Hh + h;
          unsigned short val = f2h(acc[z][i][j][r] + bb);
          if (z == 0) {
            Qb[((size_t)bh * Nseq + is) * 64 + d] = val;
          } else if (z == 1) {
            int jt = is >> 4, kf2 = d >> 5, l = ((d >> 3) & 3) * 16 + (is & 15), e = d & 7;
            KF[(((size_t)bh * 32 + jt) * 2 + kf2) * 512 + l * 8 + e] = val;
          } else {
            int dt = d >> 4, ks = is >> 5, l = ((is >> 3) & 3) * 16 + (d & 15), e = is & 7;
            VF[(((size_t)bh * 4 + dt) * 16 + ks) * 512 + l * 8 + e] = val;
          }
        }
      }
  }
}

// ---------------------------------------------------------------------------
// attn_fused v5: v3 structure + minimal zero-init. KEY CHANGE: launch_bounds
// (256,3) not (256,4) — LDS (40.6 KB) limits to 3 blocks/CU regardless, so
// the 128-VGPR cap of (,4) only forced scratch spills of the ~110-reg live
// state (sv 64 + svp 32 + q 16) across barriers. 168-VGPR budget = no spills,
// same occupancy. No setprio (4-wave lockstep block = m190 regime, hurts).
// ---------------------------------------------------------------------------
__global__ __launch_bounds__(256, 3) void attn_fused(
    const unsigned short* __restrict__ Qb,
    const unsigned short* __restrict__ KF,
    const unsigned short* __restrict__ VF,
    const float* __restrict__ Pkt,
    const unsigned short* __restrict__ PvF2,
    unsigned short* __restrict__ AwF) {
  const int flat = blockIdx.x;
  const int h = flat & 7;
  const int grp = flat >> 3;
  const int b = grp >> 4;
  const int p = grp & 15;
  const int itA = (p >> 1) * 4 + (p & 1);  // pairs {it, it+2}
  const int i0A = itA * 16;
  const int bh = b * Hh + h;
  const int tid = threadIdx.x, w = tid >> 6, lane = tid & 63;
  const int lo = lane & 15, quad = lane >> 4;

  __shared__ __align__(16) unsigned short pstA[16 * STR + 512];
  __shared__ __align__(16) unsigned short pstB[16 * STR + 512];
  __shared__ float pk_lds[560];
  __shared__ float redm[128];
  __shared__ float redl[128];

  const int TB = 464 - i0A;

  // minimal zero-init: only read-but-unwritten pad. 96 int4 per strip =
  // 32 row-heads (16 rows x 16 shorts) + 64 tail (512 shorts).
  {
    int4 z4; z4.x = z4.y = z4.z = z4.w = 0;
    int c = tid;
    if (c < 96) {
      int addr = (c < 32) ? ((c >> 1) * STR + (c & 1) * 8)
                          : (16 * STR + (c - 32) * 8);
      *(int4*)(pstA + addr) = z4;
    } else if (c < 192) {
      int c2 = c - 96;
      int addr = (c2 < 32) ? ((c2 >> 1) * STR + (c2 & 1) * 8)
                           : (16 * STR + (c2 - 32) * 8);
      *(int4*)(pstB + addr) = z4;
    }
  }
  for (int c = tid; c < 140; c += 256)
    *(float4*)(pk_lds + c * 4) = *(const float4*)(Pkt + (size_t)h * 1040 + TB + c * 4);

  const unsigned short* qA = Qb + ((size_t)bh * Nseq + i0A + lo) * 64;
  const unsigned short* qB = Qb + ((size_t)bh * Nseq + i0A + 32 + lo) * 64;
  half8 qa0 = *(const half8*)(qA + quad * 8);
  half8 qa1 = *(const half8*)(qA + 32 + quad * 8);
  half8 qb0 = *(const half8*)(qB + quad * 8);
  half8 qb1 = *(const half8*)(qB + 32 + quad * 8);

  const unsigned short* KFb = KF + ((size_t)bh * 64 + (size_t)w * 16) * 512 + lane * 8;
  const unsigned short* VFb = VF + ((size_t)bh * 4 + w) * 16 * 512 + lane * 8;
  const int aP = (TB >> 4) & 1, gtB = TB >> 5;
  const unsigned short* PFb =
      PvF2 + ((((size_t)aP * Hh + h) * 4 + w) * 32 + gtB) * 512 + lane * 8;

  __syncthreads();  // B1

  // ---------------- Phase 1: scores ----------------
  float svA[8][4], svB[8][4];
  float mA[4] = {-1e30f, -1e30f, -1e30f, -1e30f};
  float mB[4] = {-1e30f, -1e30f, -1e30f, -1e30f};
#pragma unroll
  for (int g = 0; g < 8; ++g) {
    half8 k0 = *(const half8*)(KFb + (size_t)(2 * g + 0) * 512);
    half8 k1 = *(const half8*)(KFb + (size_t)(2 * g + 1) * 512);
    f32x4 cA = {0.f, 0.f, 0.f, 0.f};
    f32x4 cB = {0.f, 0.f, 0.f, 0.f};
    cA = __builtin_amdgcn_mfma_f32_16x16x32_f16(qa0, k0, cA, 0, 0, 0);
    cA = __builtin_amdgcn_mfma_f32_16x16x32_f16(qa1, k1, cA, 0, 0, 0);
    cB = __builtin_amdgcn_mfma_f32_16x16x32_f16(qb0, k0, cB, 0, 0, 0);
    cB = __builtin_amdgcn_mfma_f32_16x16x32_f16(qb1, k1, cB, 0, 0, 0);
    int j = w * 128 + g * 16 + lo;
#pragma unroll
    for (int r = 0; r < 4; ++r) {
      int rl = quad * 4 + r;
      int idx = j - rl + 15;
      float vA = (cA[r] + pk_lds[idx + 32]) * 0.125f;
      float vB = (cB[r] + pk_lds[idx]) * 0.125f;
      svA[g][r] = vA; svB[g][r] = vB;
      mA[r] = fmaxf(mA[r], vA);
      mB[r] = fmaxf(mB[r], vB);
    }
  }

  // ---------------- softmax x2 ----------------
#pragma unroll
  for (int m = 1; m <= 8; m <<= 1)
#pragma unroll
    for (int r = 0; r < 4; ++r) {
      mA[r] = fmaxf(mA[r], __shfl_xor(mA[r], m));
      mB[r] = fmaxf(mB[r], __shfl_xor(mB[r], m));
    }
  if (lo == 0)
#pragma unroll
    for (int r = 0; r < 4; ++r) {
      redm[(0 * 4 + w) * 16 + quad * 4 + r] = mA[r];
      redm[(1 * 4 + w) * 16 + quad * 4 + r] = mB[r];
    }
  __syncthreads();  // B2
  float mfA[4], mfB[4];
#pragma unroll
  for (int r = 0; r < 4; ++r) {
    int rl = quad * 4 + r;
    mfA[r] = fmaxf(fmaxf(redm[rl], redm[16 + rl]), fmaxf(redm[32 + rl], redm[48 + rl]));
    mfB[r] = fmaxf(fmaxf(redm[64 + rl], redm[80 + rl]), fmaxf(redm[96 + rl], redm[112 + rl]));
  }
  float lA[4] = {0.f, 0.f, 0.f, 0.f}, lB[4] = {0.f, 0.f, 0.f, 0.f};
  unsigned int svp[8][4];  // packed fp16 exp values: lo=A, hi=B
#pragma unroll
  for (int s = 0; s < 8; ++s)
#pragma unroll
    for (int r = 0; r < 4; ++r) {
      float eA = __expf(svA[s][r] - mfA[r]);
      float eB = __expf(svB[s][r] - mfB[r]);
      lA[r] += eA; lB[r] += eB;
      svp[s][r] = (unsigned int)f2h(eA) | ((unsigned int)f2h(eB) << 16);
    }
#pragma unroll
  for (int m = 1; m <= 8; m <<= 1)
#pragma unroll
    for (int r = 0; r < 4; ++r) {
      lA[r] += __shfl_xor(lA[r], m);
      lB[r] += __shfl_xor(lB[r], m);
    }
  if (lo == 0)
#pragma unroll
    for (int r = 0; r < 4; ++r) {
      redl[(0 * 4 + w) * 16 + quad * 4 + r] = lA[r];
      redl[(1 * 4 + w) * 16 + quad * 4 + r] = lB[r];
    }
  __syncthreads();  // B3
  float liA[4], liB[4];
#pragma unroll
  for (int r = 0; r < 4; ++r) {
    int rl = quad * 4 + r;
    liA[r] = 1.f / (redl[rl] + redl[16 + rl] + redl[32 + rl] + redl[48 + rl]);
    liB[r] = 1.f / (redl[64 + rl] + redl[80 + rl] + redl[96 + rl] + redl[112 + rl]);
#pragma unroll
    for (int s = 0; s < 8; ++s) {
      int j = w * 128 + s * 16 + lo;
      pstA[rl * STR + 16 + j] = (unsigned short)svp[s][r];
      pstB[rl * STR + 16 + j] = (unsigned short)(svp[s][r] >> 16);
    }
  }
  __syncthreads();  // B4

  // ---------------- Phase 2: P@V ----------------
  f32x4 oVA = {0.f, 0.f, 0.f, 0.f}, oVB = {0.f, 0.f, 0.f, 0.f};
#pragma unroll
  for (int g = 0; g < 8; ++g) {
    half8 v0 = *(const half8*)(VFb + (size_t)(2 * g + 0) * 512);
    half8 v1 = *(const half8*)(VFb + (size_t)(2 * g + 1) * 512);
#pragma unroll
    for (int c = 0; c < 2; ++c) {
      int ks = 2 * g + c;
      half8 vv = c ? v1 : v0;
      half8 pA = *(const half8*)(&pstA[lo * STR + 16 + ks * 32 + quad * 8]);
      half8 pB = *(const half8*)(&pstB[lo * STR + 16 + ks * 32 + quad * 8]);
      oVA = __builtin_amdgcn_mfma_f32_16x16x32_f16(pA, vv, oVA, 0, 0, 0);
      oVB = __builtin_amdgcn_mfma_f32_16x16x32_f16(pB, vv, oVB, 0, 0, 0);
    }
  }
  __syncthreads();  // B5

  // ---------------- in-place skewed rewrite ----------------
#pragma unroll
  for (int r = 0; r < 4; ++r) {
    int rl = quad * 4 + r;
#pragma unroll
    for (int s = 0; s < 8; ++s) {
      int j = w * 128 + s * 16 + lo;
      int x = j - rl + 15;
      unsigned int pv = svp[s][r];
      if (w == 3 && s == 7) {
        int addr = (x < 512) ? (rl * STR + x) : (16 * STR + rl * 32 + (x - 512));
        pstA[addr] = (unsigned short)pv;
        pstB[addr] = (unsigned short)(pv >> 16);
      } else {
        pstA[rl * STR + x] = (unsigned short)pv;
        pstB[rl * STR + x] = (unsigned short)(pv >> 16);
      }
    }
  }
  __syncthreads();  // B6

  // ---------------- Phase 2b: P'@Pv ----------------
  f32x4 oPA = {0.f, 0.f, 0.f, 0.f}, oPB = {0.f, 0.f, 0.f, 0.f};
#pragma unroll
  for (int g = 0; g < 9; ++g) {
    half8 p0 = *(const half8*)(PFb + (size_t)(2 * g + 0) * 512);
    half8 p1 = *(const half8*)(PFb + (size_t)(2 * g + 1) * 512);
#pragma unroll
    for (int c = 0; c < 2; ++c) {
      int cg = 2 * g + c;
      half8 pvf = c ? p1 : p0;
      if (cg < 17) {
        const unsigned short* src = (cg < 16)
            ? &pstB[lo * STR + cg * 32 + quad * 8]
            : &pstB[16 * STR + lo * 32 + quad * 8];
        oPB = __builtin_amdgcn_mfma_f32_16x16x32_f16(*(const half8*)src, pvf, oPB, 0, 0, 0);
      }
      if (cg >= 1) {
        int ksA = cg - 1;
        const unsigned short* src = (ksA < 16)
            ? &pstA[lo * STR + ksA * 32 + quad * 8]
            : &pstA[16 * STR + lo * 32 + quad * 8];
        oPA = __builtin_amdgcn_mfma_f32_16x16x32_f16(*(const half8*)src, pvf, oPA, 0, 0, 0);
      }
    }
  }

  // epilogue x2: single A-frag-major AwF, normalize here
  const int kf = h * 2 + (w >> 1);
  const int lhi = ((w & 1) * 2 + (lo >> 3)) * 16;
#pragma unroll
  for (int t = 0; t < 2; ++t) {
    int mc = b * 32 + itA + t * 2;
#pragma unroll
    for (int r = 0; r < 4; ++r) {
      float ov = t ? (oVB[r] + oPB[r]) * liB[r] : (oVA[r] + oPA[r]) * liA[r];
      size_t fl = (((size_t)mc * 16 + kf) * 64 + lhi + quad * 4 + r) * 8 + (lo & 7);
      AwF[fl] = f2h(ov);
    }
  }
}

// ---------------------------------------------------------------------------
// gemm_final: single-term fp16 MFMA, BK=64 staged. out = AwF @ WoF + bo.
// ---------------------------------------------------------------------------
__global__ __launch_bounds__(256, 2) void gemm_final(const unsigned short* __restrict__ AF,
                                                     const unsigned short* __restrict__ BF,
                                                     const float* __restrict__ bo,
                                                     float* __restrict__ out) {
  const int flat = blockIdx.x;
  const int xcd = flat & 7, g = flat >> 3;
  const int by = xcd * 8 + (g & 7), bx = g >> 3;
  const int bm = by * 64, bn = bx * 64;
  const int mc0 = bm >> 4, nc0 = bn >> 4;
  const int tid = threadIdx.x, w = tid >> 6, lane = tid & 63;
  const int lo = lane & 15, quad = lane >> 4;
  const int mh = (w >> 1) * 2, nh = (w & 1) * 2;

  __shared__ __align__(16) unsigned short stg[2][16 * 512];

  const unsigned short* srcArr = (w < 2) ? AF : BF;
  const int rowbase = ((w < 2) ? mc0 : nc0) + (w & 1) * 2;

#define STAGE2(buf, ks)                                                            \
  do {                                                                             \
    _Pragma("unroll") for (int t = 0; t < 4; ++t) {                                \
      gl_lds16(srcArr +                                                            \
                   (((size_t)(rowbase + (t >> 1)) * 16 + 2 * (ks) + (t & 1)) * 512) + \
                   lane * 8,                                                       \
               &stg[buf][(w * 4 + t) * 512]);                                      \
    }                                                                              \
  } while (0)

  f32x4 acc[2][2] = {};
  STAGE2(0, 0);
  int cur = 0;
#pragma unroll
  for (int ks = 0; ks < 8; ++ks) {
    __syncthreads();
    if (ks < 7) STAGE2(cur ^ 1, ks + 1);
#pragma unroll
    for (int kf = 0; kf < 2; ++kf) {
      half8 af[2], bf[2];
#pragma unroll
      for (int i = 0; i < 2; ++i)
        af[i] = *(const half8*)(&stg[cur][((mh + i) * 2 + kf) * 512 + lane * 8]);
#pragma unroll
      for (int j = 0; j < 2; ++j)
        bf[j] = *(const half8*)(&stg[cur][(8 + (nh + j) * 2 + kf) * 512 + lane * 8]);
#pragma unroll
      for (int i = 0; i < 2; ++i)
#pragma unroll
        for (int j = 0; j < 2; ++j)
          acc[i][j] = __builtin_amdgcn_mfma_f32_16x16x32_f16(af[i], bf[j], acc[i][j], 0, 0, 0);
    }
    cur ^= 1;
  }
#undef STAGE2

  const int mt = (w >> 1) * 32, nt = (w & 1) * 32;
#pragma unroll
  for (int i = 0; i < 2; ++i)
#pragma unroll
    for (int j = 0; j < 2; ++j) {
      int col = bn + nt + j * 16 + lo;
      float bb = bo[col];
#pragma unroll
      for (int r = 0; r < 4; ++r) {
        int row = bm + mt + i * 16 + quad * 4 + r;
        out[(size_t)row * DM + col] = acc[i][j][r] + bb;
      }
    }
}

// ---------------------------------------------------------------------------
extern "C" void kernel_launch(void* const* d_in, const int* in_sizes, int n_in,
                              void* d_out, int out_size, void* d_ws, size_t ws_size,
                              hipStream_t stream) {
  const float* X  = (const float*)d_in[0];
  const float* Wq = (const float*)d_in[1];
  const float* bq = (const float*)d_in[2];
  const float* Wk = (const float*)d_in[3];
  const float* bk = (const float*)d_in[4];
  const float* Wv = (const float*)d_in[5];
  const float* bv = (const float*)d_in[6];
  const float* Wo = (const float*)d_in[7];
  const float* bo = (const float*)d_in[8];
  const float* Pk = (const float*)d_in[9];
  const float* Pv = (const float*)d_in[10];
  float* out = (float*)d_out;

  char* p = (char*)d_ws;
  const size_t szX    = (size_t)Bc * Nseq * DM * 2;        // 4 MB
  const size_t szW    = (size_t)DM * DM * 2;               // 512 KB
  const size_t szPkt  = (size_t)Hh * 1040 * 4;
  const size_t szPvF2 = (size_t)2 * Hh * 4 * 32 * 512 * 2; // 2 MB
  const size_t szQKV  = (size_t)Bc * Hh * Nseq * 64 * 2;   // 4 MB
  unsigned short* XbF = (unsigned short*)p; p += szX;
  unsigned short* WqF = (unsigned short*)p; p += szW;
  unsigned short* WkF = (unsigned short*)p; p += szW;
  unsigned short* WvF = (unsigned short*)p; p += szW;
  unsigned short* WoF = (unsigned short*)p; p += szW;
  float*          Pkt = (float*)p;          p += (szPkt + 255) & ~(size_t)255;
  unsigned short* PvF2 = (unsigned short*)p; p += szPvF2;
  unsigned short* Qb  = (unsigned short*)p; p += szQKV;
  unsigned short* KF  = (unsigned short*)p; p += szQKV;
  unsigned short* VF  = (unsigned short*)p; p += szQKV;
  unsigned short* AwF = (unsigned short*)p; p += szX;

  dim3 blk(256);
  prep_all<<<dim3(2216), blk, 0, stream>>>(X, Wq, Wk, Wv, Wo, Pk, Pv,
                                           XbF, WqF, WkF, WvF, WoF, Pkt, PvF2);
  gemm_qkv<<<dim3(512), blk, 0, stream>>>(XbF, WqF, WkF, WvF, bq, bk, bv, Qb, KF, VF);
  attn_fused<<<dim3(1024), blk, 0, stream>>>(Qb, KF, VF, Pkt, PvF2, AwF);
  gemm_final<<<dim3(512), blk, 0, stream>>>(AwF, WoF, bo, out);
}

// Round 7
// 124.804 us; speedup vs baseline: 1.4073x; 1.0042x over previous
//
#include <hip/hip_runtime.h>
#include <math.h>

#define Bc 8
#define Nseq 512
#define DM 512
#define Hh 8
#define NUMREL 1023
#define ZOFF 511   // NUMREL/2
#define STR 552    // pstrip row stride (shorts)

typedef _Float16 half8 __attribute__((ext_vector_type(8)));
typedef float f32x4 __attribute__((ext_vector_type(4)));

__device__ __forceinline__ unsigned short f2h(float f) {
  _Float16 h = (_Float16)f;  // v_cvt_f16_f32, RNE
  return __builtin_bit_cast(unsigned short, h);
}

typedef __attribute__((address_space(3))) unsigned int as3_uint;
typedef __attribute__((address_space(1))) const unsigned int as1_uint;
__device__ __forceinline__ void gl_lds16(const void* g, void* l) {
  __builtin_amdgcn_global_load_lds((as1_uint*)g, (as3_uint*)l, 16, 0, 0);
}

// ---------------------------------------------------------------------------
// prep_all: bid [0,1024) X->XbF (A-frag-major fp16); [1024,2048) W->WqF/WkF/
// WvF/WoF (B-frag-major fp16); [2048,2088) Pk->Pkt fp32; [2088,2216) Pv->PvF2.
// ---------------------------------------------------------------------------
__global__ __launch_bounds__(256) void prep_all(
    const float* __restrict__ X, const float* __restrict__ Wq,
    const float* __restrict__ Wk, const float* __restrict__ Wv,
    const float* __restrict__ Wo, const float* __restrict__ Pk,
    const float* __restrict__ Pv,
    unsigned short* __restrict__ XbF, unsigned short* __restrict__ WqF,
    unsigned short* __restrict__ WkF, unsigned short* __restrict__ WvF,
    unsigned short* __restrict__ WoF,
    float* __restrict__ Pkt, unsigned short* __restrict__ PvF2) {
  __shared__ float tbuf[5120];
  const int bid = blockIdx.x;
  const int tid = threadIdx.x;

  if (bid < 1024) {
    const int w = tid >> 6, lane = tid & 63;
    const int r = bid * 4 + w;
    const float* src = X + (size_t)r * DM + lane * 8;
    float4 a = *(const float4*)src;
    float4 b = *(const float4*)(src + 4);
    ushort4 o0, o1;
    o0.x = f2h(a.x); o0.y = f2h(a.y); o0.z = f2h(a.z); o0.w = f2h(a.w);
    o1.x = f2h(b.x); o1.y = f2h(b.y); o1.z = f2h(b.z); o1.w = f2h(b.w);
    const int mc = r >> 4, kf = lane >> 2, l = (lane & 3) * 16 + (r & 15);
    size_t flat = (((size_t)mc * 16 + kf) * 64 + l) * 8;
    *(ushort4*)(XbF + flat) = o0;
    *(ushort4*)(XbF + flat + 4) = o1;
  } else if (bid < 2048) {
    const int idx = bid - 1024;
    const int z = idx >> 8, r256 = idx & 255;
    const int bx = r256 & 15, by = r256 >> 4;
    const float* src = z == 0 ? Wq : z == 1 ? Wk : z == 2 ? Wv : Wo;
    unsigned short* dst = z == 0 ? WqF : z == 1 ? WkF : z == 2 ? WvF : WoF;
    const int k0 = by * 32, n0 = bx * 32;
#pragma unroll
    for (int u = 0; u < 4; ++u) {
      int i2 = u * 256 + tid, r = i2 >> 5, c = i2 & 31;
      tbuf[r * 33 + c] = src[(size_t)(k0 + r) * DM + n0 + c];
    }
    __syncthreads();
    const int ncl = tid >> 7, l = (tid >> 1) & 63, eh = tid & 1;
    const int nl = ncl * 16 + (l & 15);
    const int klb = (l >> 4) * 8 + eh * 4;
    ushort4 o;
    o.x = f2h(tbuf[(klb + 0) * 33 + nl]);
    o.y = f2h(tbuf[(klb + 1) * 33 + nl]);
    o.z = f2h(tbuf[(klb + 2) * 33 + nl]);
    o.w = f2h(tbuf[(klb + 3) * 33 + nl]);
    size_t flat = (((size_t)((n0 >> 4) + ncl) * 16 + (k0 >> 5)) * 64 + l) * 8 + eh * 4;
    *(ushort4*)(dst + flat) = o;
  } else if (bid < 2088) {
    const int idx = bid - 2048;
    const int gx = idx % 5, h = idx / 5;
    const int g = gx * 256 + tid;
    if (g < 1040)
      Pkt[(size_t)h * 1040 + g] = (g < NUMREL) ? Pk[(size_t)g * Hh + h] : 0.f;
  } else {
    const int idx = bid - 2088;
    const int gx = idx & 15, h = idx >> 4;
    const int g0 = gx * 64;
#pragma unroll
    for (int u = 0; u < 20; ++u) {
      int i2 = u * 256 + tid, r = i2 >> 6, c = i2 & 63;
      int g = g0 + r;
      tbuf[r * 64 + c] = (g < NUMREL) ? Pv[(size_t)g * 512 + h * 64 + c] : 0.f;
    }
    __syncthreads();
#pragma unroll
    for (int av = 0; av < 2; ++av)
#pragma unroll
      for (int gtl = 0; gtl < 2; ++gtl) {
        int gt = (g0 >> 5) + gtl;
#pragma unroll
        for (int dt = 0; dt < 4; ++dt) {
          size_t base = ((((size_t)av * Hh + h) * 4 + dt) * 32 + gt) * 512;
          int i2 = tid * 2;
          int l = i2 >> 3, e = i2 & 7;
          int gr = av * 16 + gtl * 32 + (l >> 4) * 8 + e;
          int dcol = dt * 16 + (l & 15);
          ushort2 o;
          o.x = f2h(tbuf[gr * 64 + dcol]);
          o.y = f2h(tbuf[(gr + 1) * 64 + dcol]);
          *(ushort2*)(PvF2 + base + i2) = o;
        }
      }
  }
}

// ---------------------------------------------------------------------------
// gemm_qkv v3: BK=64 staged loop (R3) + LDS-STAGED COALESCED EPILOGUE.
// Old epilogue: 48 scalar 2B scattered stores/lane -> 49 MB WRITE_SIZE (4x
// amplification, ~6us of junk HBM traffic). New: stage output tiles in the
// dead stg buffer (z=0/1 row-major [64][72], z=2 transposed [d][is]), then
// cooperative int4 stores — every destination segment is 16B-contiguous per
// lane -> full-line writes, WRITE_SIZE ~12.5 MB.
// ---------------------------------------------------------------------------
__global__ __launch_bounds__(256, 2) void gemm_qkv(const unsigned short* __restrict__ XbF,
                                                   const unsigned short* __restrict__ WqF,
                                                   const unsigned short* __restrict__ WkF,
                                                   const unsigned short* __restrict__ WvF,
                                                   const float* __restrict__ bq,
                                                   const float* __restrict__ bk,
                                                   const float* __restrict__ bv,
                                                   unsigned short* __restrict__ Qb,
                                                   unsigned short* __restrict__ KF,
                                                   unsigned short* __restrict__ VF) {
  const int flat = blockIdx.x;
  const int xcd = flat & 7, g = flat >> 3;
  const int by = xcd * 8 + (g & 7), bx = g >> 3;
  const int bm = by * 64, bn = bx * 64;
  const int mc0 = bm >> 4, nc0 = bn >> 4;
  const int tid = threadIdx.x, w = tid >> 6, lane = tid & 63;
  const int lo = lane & 15, quad = lane >> 4;
  const int mh = (w >> 1) * 2, nh = (w & 1) * 2;

  __shared__ __align__(16) unsigned short stg[2][32 * 512];

  const unsigned short* srcArr = w == 0 ? XbF : w == 1 ? WqF : w == 2 ? WkF : WvF;
  const int rowbase = (w == 0) ? mc0 : nc0;

#define STAGE(buf, ks)                                                             \
  do {                                                                             \
    _Pragma("unroll") for (int t = 0; t < 8; ++t) {                                \
      gl_lds16(srcArr +                                                            \
                   (((size_t)(rowbase + (t >> 1)) * 16 + 2 * (ks) + (t & 1)) * 512) + \
                   lane * 8,                                                       \
               &stg[buf][(w * 8 + t) * 512]);                                      \
    }                                                                              \
  } while (0)

  f32x4 acc[3][2][2] = {};
  STAGE(0, 0);
  int cur = 0;
#pragma unroll
  for (int ks = 0; ks < 8; ++ks) {
    __syncthreads();
    if (ks < 7) STAGE(cur ^ 1, ks + 1);
#pragma unroll
    for (int kf = 0; kf < 2; ++kf) {
      half8 af[2], bq_[2], bk_[2], bv_[2];
#pragma unroll
      for (int i = 0; i < 2; ++i)
        af[i] = *(const half8*)(&stg[cur][((mh + i) * 2 + kf) * 512 + lane * 8]);
#pragma unroll
      for (int j = 0; j < 2; ++j) {
        bq_[j] = *(const half8*)(&stg[cur][(8 + (nh + j) * 2 + kf) * 512 + lane * 8]);
        bk_[j] = *(const half8*)(&stg[cur][(16 + (nh + j) * 2 + kf) * 512 + lane * 8]);
        bv_[j] = *(const half8*)(&stg[cur][(24 + (nh + j) * 2 + kf) * 512 + lane * 8]);
      }
#pragma unroll
      for (int i = 0; i < 2; ++i)
#pragma unroll
        for (int j = 0; j < 2; ++j) {
          acc[0][i][j] = __builtin_amdgcn_mfma_f32_16x16x32_f16(af[i], bq_[j], acc[0][i][j], 0, 0, 0);
          acc[1][i][j] = __builtin_amdgcn_mfma_f32_16x16x32_f16(af[i], bk_[j], acc[1][i][j], 0, 0, 0);
          acc[2][i][j] = __builtin_amdgcn_mfma_f32_16x16x32_f16(af[i], bv_[j], acc[2][i][j], 0, 0, 0);
        }
    }
    cur ^= 1;
  }
#undef STAGE

  // ---- LDS-staged epilogue ----
  __syncthreads();  // all MFMA reads of stg complete; stg reusable
  unsigned short* tile0 = &stg[0][0];          // z=0 (Qb) row-major [64][72]
  unsigned short* tile1 = tile0 + 64 * 72;     // z=1 (KF) row-major [64][72]
  unsigned short* tile2 = tile1 + 64 * 72;     // z=2 (VF) transposed [d][is], [64][72]
  {
    const int mt = (w >> 1) * 32, nt = (w & 1) * 32;
#pragma unroll
    for (int i = 0; i < 2; ++i)
#pragma unroll
      for (int j = 0; j < 2; ++j) {
        int colL = nt + j * 16 + lo;
        float b0 = bq[bn + colL], b1 = bk[bn + colL], b2 = bv[bn + colL];
#pragma unroll
        for (int r = 0; r < 4; ++r) {
          int rowL = mt + i * 16 + quad * 4 + r;
          tile0[rowL * 72 + colL] = f2h(acc[0][i][j][r] + b0);
          tile1[rowL * 72 + colL] = f2h(acc[1][i][j][r] + b1);
        }
        ushort4 ov;
        ov.x = f2h(acc[2][i][j][0] + b2);
        ov.y = f2h(acc[2][i][j][1] + b2);
        ov.z = f2h(acc[2][i][j][2] + b2);
        ov.w = f2h(acc[2][i][j][3] + b2);
        int rowL0 = mt + i * 16 + quad * 4;
        *(ushort4*)(tile2 + colL * 72 + rowL0) = ov;
      }
  }
  __syncthreads();
  {
    const int b = bm >> 9, isBase = bm & 511, h = bn >> 6;
    const int bh = b * Hh + h;
    const int jtB = isBase >> 4, ksB = isBase >> 5;
    // z=0: Qb — 64 rows x 128B contiguous
    unsigned short* Qbase = Qb + ((size_t)bh * Nseq + isBase) * 64;
#pragma unroll
    for (int p2 = 0; p2 < 2; ++p2) {
      int rowL = p2 * 32 + (tid >> 3);
      int c8 = (tid & 7) * 8;
      int4 v = *(int4*)(tile0 + rowL * 72 + c8);
      *(int4*)(Qbase + rowL * 64 + c8) = v;
    }
    // z=1: KF — 32 segments of 128 u16: seg(sjt,kf2,dd2), elem (is&15)*8+(d&7)
    unsigned short* K64 = KF + (((size_t)bh * 32 + jtB) * 2) * 512;
#pragma unroll
    for (int p2 = 0; p2 < 2; ++p2) {
      int s = p2 * 16 + (tid >> 4);
      int sjt = s >> 3, kf2 = (s >> 2) & 1, dd2 = s & 3;
      int e16 = tid & 15;
      int4 v = *(int4*)(tile1 + (sjt * 16 + e16) * 72 + kf2 * 32 + dd2 * 8);
      *(int4*)(K64 + ((size_t)sjt * 2 + kf2) * 512 + dd2 * 128 + e16 * 8) = v;
    }
    // z=2: VF — 32 segments of 128 u16: seg(dt,sks,i3), elem (d&15)*8+(is&7)
    unsigned short* V64 = VF + ((size_t)bh * 4) * 16 * 512 + (size_t)ksB * 512;
#pragma unroll
    for (int p2 = 0; p2 < 2; ++p2) {
      int s = p2 * 16 + (tid >> 4);
      int dt = s >> 3, sks = (s >> 2) & 1, i3 = s & 3;
      int e16 = tid & 15;
      int4 v = *(int4*)(tile2 + (dt * 16 + e16) * 72 + sks * 32 + i3 * 8);
      *(int4*)(V64 + ((size_t)dt * 16 + sks) * 512 + i3 * 128 + e16 * 8) = v;
    }
  }
}

// ---------------------------------------------------------------------------
// attn_fused v5: direct global->VGPR K/V/Pv + in-place skewed P rewrite +
// minimal zero-init + launch_bounds(256,3) (168-VGPR budget matches the
// LDS-limited 3 blocks/CU; (,4)'s 128-cap forced spills). No setprio.
// ---------------------------------------------------------------------------
__global__ __launch_bounds__(256, 3) void attn_fused(
    const unsigned short* __restrict__ Qb,
    const unsigned short* __restrict__ KF,
    const unsigned short* __restrict__ VF,
    const float* __restrict__ Pkt,
    const unsigned short* __restrict__ PvF2,
    unsigned short* __restrict__ AwF) {
  const int flat = blockIdx.x;
  const int h = flat & 7;
  const int grp = flat >> 3;
  const int b = grp >> 4;
  const int p = grp & 15;
  const int itA = (p >> 1) * 4 + (p & 1);  // pairs {it, it+2}
  const int i0A = itA * 16;
  const int bh = b * Hh + h;
  const int tid = threadIdx.x, w = tid >> 6, lane = tid & 63;
  const int lo = lane & 15, quad = lane >> 4;

  __shared__ __align__(16) unsigned short pstA[16 * STR + 512];
  __shared__ __align__(16) unsigned short pstB[16 * STR + 512];
  __shared__ float pk_lds[560];
  __shared__ float redm[128];
  __shared__ float redl[128];

  const int TB = 464 - i0A;

  // minimal zero-init: only read-but-unwritten pad. 96 int4 per strip =
  // 32 row-heads (16 rows x 16 shorts) + 64 tail (512 shorts).
  {
    int4 z4; z4.x = z4.y = z4.z = z4.w = 0;
    int c = tid;
    if (c < 96) {
      int addr = (c < 32) ? ((c >> 1) * STR + (c & 1) * 8)
                          : (16 * STR + (c - 32) * 8);
      *(int4*)(pstA + addr) = z4;
    } else if (c < 192) {
      int c2 = c - 96;
      int addr = (c2 < 32) ? ((c2 >> 1) * STR + (c2 & 1) * 8)
                           : (16 * STR + (c2 - 32) * 8);
      *(int4*)(pstB + addr) = z4;
    }
  }
  for (int c = tid; c < 140; c += 256)
    *(float4*)(pk_lds + c * 4) = *(const float4*)(Pkt + (size_t)h * 1040 + TB + c * 4);

  const unsigned short* qA = Qb + ((size_t)bh * Nseq + i0A + lo) * 64;
  const unsigned short* qB = Qb + ((size_t)bh * Nseq + i0A + 32 + lo) * 64;
  half8 qa0 = *(const half8*)(qA + quad * 8);
  half8 qa1 = *(const half8*)(qA + 32 + quad * 8);
  half8 qb0 = *(const half8*)(qB + quad * 8);
  half8 qb1 = *(const half8*)(qB + 32 + quad * 8);

  const unsigned short* KFb = KF + ((size_t)bh * 64 + (size_t)w * 16) * 512 + lane * 8;
  const unsigned short* VFb = VF + ((size_t)bh * 4 + w) * 16 * 512 + lane * 8;
  const int aP = (TB >> 4) & 1, gtB = TB >> 5;
  const unsigned short* PFb =
      PvF2 + ((((size_t)aP * Hh + h) * 4 + w) * 32 + gtB) * 512 + lane * 8;

  __syncthreads();  // B1

  // ---------------- Phase 1: scores ----------------
  float svA[8][4], svB[8][4];
  float mA[4] = {-1e30f, -1e30f, -1e30f, -1e30f};
  float mB[4] = {-1e30f, -1e30f, -1e30f, -1e30f};
#pragma unroll
  for (int g = 0; g < 8; ++g) {
    half8 k0 = *(const half8*)(KFb + (size_t)(2 * g + 0) * 512);
    half8 k1 = *(const half8*)(KFb + (size_t)(2 * g + 1) * 512);
    f32x4 cA = {0.f, 0.f, 0.f, 0.f};
    f32x4 cB = {0.f, 0.f, 0.f, 0.f};
    cA = __builtin_amdgcn_mfma_f32_16x16x32_f16(qa0, k0, cA, 0, 0, 0);
    cA = __builtin_amdgcn_mfma_f32_16x16x32_f16(qa1, k1, cA, 0, 0, 0);
    cB = __builtin_amdgcn_mfma_f32_16x16x32_f16(qb0, k0, cB, 0, 0, 0);
    cB = __builtin_amdgcn_mfma_f32_16x16x32_f16(qb1, k1, cB, 0, 0, 0);
    int j = w * 128 + g * 16 + lo;
#pragma unroll
    for (int r = 0; r < 4; ++r) {
      int rl = quad * 4 + r;
      int idx = j - rl + 15;
      float vA = (cA[r] + pk_lds[idx + 32]) * 0.125f;
      float vB = (cB[r] + pk_lds[idx]) * 0.125f;
      svA[g][r] = vA; svB[g][r] = vB;
      mA[r] = fmaxf(mA[r], vA);
      mB[r] = fmaxf(mB[r], vB);
    }
  }

  // ---------------- softmax x2 ----------------
#pragma unroll
  for (int m = 1; m <= 8; m <<= 1)
#pragma unroll
    for (int r = 0; r < 4; ++r) {
      mA[r] = fmaxf(mA[r], __shfl_xor(mA[r], m));
      mB[r] = fmaxf(mB[r], __shfl_xor(mB[r], m));
    }
  if (lo == 0)
#pragma unroll
    for (int r = 0; r < 4; ++r) {
      redm[(0 * 4 + w) * 16 + quad * 4 + r] = mA[r];
      redm[(1 * 4 + w) * 16 + quad * 4 + r] = mB[r];
    }
  __syncthreads();  // B2
  float mfA[4], mfB[4];
#pragma unroll
  for (int r = 0; r < 4; ++r) {
    int rl = quad * 4 + r;
    mfA[r] = fmaxf(fmaxf(redm[rl], redm[16 + rl]), fmaxf(redm[32 + rl], redm[48 + rl]));
    mfB[r] = fmaxf(fmaxf(redm[64 + rl], redm[80 + rl]), fmaxf(redm[96 + rl], redm[112 + rl]));
  }
  float lA[4] = {0.f, 0.f, 0.f, 0.f}, lB[4] = {0.f, 0.f, 0.f, 0.f};
  unsigned int svp[8][4];  // packed fp16 exp values: lo=A, hi=B
#pragma unroll
  for (int s = 0; s < 8; ++s)
#pragma unroll
    for (int r = 0; r < 4; ++r) {
      float eA = __expf(svA[s][r] - mfA[r]);
      float eB = __expf(svB[s][r] - mfB[r]);
      lA[r] += eA; lB[r] += eB;
      svp[s][r] = (unsigned int)f2h(eA) | ((unsigned int)f2h(eB) << 16);
    }
#pragma unroll
  for (int m = 1; m <= 8; m <<= 1)
#pragma unroll
    for (int r = 0; r < 4; ++r) {
      lA[r] += __shfl_xor(lA[r], m);
      lB[r] += __shfl_xor(lB[r], m);
    }
  if (lo == 0)
#pragma unroll
    for (int r = 0; r < 4; ++r) {
      redl[(0 * 4 + w) * 16 + quad * 4 + r] = lA[r];
      redl[(1 * 4 + w) * 16 + quad * 4 + r] = lB[r];
    }
  __syncthreads();  // B3
  float liA[4], liB[4];
#pragma unroll
  for (int r = 0; r < 4; ++r) {
    int rl = quad * 4 + r;
    liA[r] = 1.f / (redl[rl] + redl[16 + rl] + redl[32 + rl] + redl[48 + rl]);
    liB[r] = 1.f / (redl[64 + rl] + redl[80 + rl] + redl[96 + rl] + redl[112 + rl]);
#pragma unroll
    for (int s = 0; s < 8; ++s) {
      int j = w * 128 + s * 16 + lo;
      pstA[rl * STR + 16 + j] = (unsigned short)svp[s][r];
      pstB[rl * STR + 16 + j] = (unsigned short)(svp[s][r] >> 16);
    }
  }
  __syncthreads();  // B4

  // ---------------- Phase 2: P@V ----------------
  f32x4 oVA = {0.f, 0.f, 0.f, 0.f}, oVB = {0.f, 0.f, 0.f, 0.f};
#pragma unroll
  for (int g = 0; g < 8; ++g) {
    half8 v0 = *(const half8*)(VFb + (size_t)(2 * g + 0) * 512);
    half8 v1 = *(const half8*)(VFb + (size_t)(2 * g + 1) * 512);
#pragma unroll
    for (int c = 0; c < 2; ++c) {
      int ks = 2 * g + c;
      half8 vv = c ? v1 : v0;
      half8 pA = *(const half8*)(&pstA[lo * STR + 16 + ks * 32 + quad * 8]);
      half8 pB = *(const half8*)(&pstB[lo * STR + 16 + ks * 32 + quad * 8]);
      oVA = __builtin_amdgcn_mfma_f32_16x16x32_f16(pA, vv, oVA, 0, 0, 0);
      oVB = __builtin_amdgcn_mfma_f32_16x16x32_f16(pB, vv, oVB, 0, 0, 0);
    }
  }
  __syncthreads();  // B5

  // ---------------- in-place skewed rewrite ----------------
#pragma unroll
  for (int r = 0; r < 4; ++r) {
    int rl = quad * 4 + r;
#pragma unroll
    for (int s = 0; s < 8; ++s) {
      int j = w * 128 + s * 16 + lo;
      int x = j - rl + 15;
      unsigned int pv = svp[s][r];
      if (w == 3 && s == 7) {
        int addr = (x < 512) ? (rl * STR + x) : (16 * STR + rl * 32 + (x - 512));
        pstA[addr] = (unsigned short)pv;
        pstB[addr] = (unsigned short)(pv >> 16);
      } else {
        pstA[rl * STR + x] = (unsigned short)pv;
        pstB[rl * STR + x] = (unsigned short)(pv >> 16);
      }
    }
  }
  __syncthreads();  // B6

  // ---------------- Phase 2b: P'@Pv ----------------
  f32x4 oPA = {0.f, 0.f, 0.f, 0.f}, oPB = {0.f, 0.f, 0.f, 0.f};
#pragma unroll
  for (int g = 0; g < 9; ++g) {
    half8 p0 = *(const half8*)(PFb + (size_t)(2 * g + 0) * 512);
    half8 p1 = *(const half8*)(PFb + (size_t)(2 * g + 1) * 512);
#pragma unroll
    for (int c = 0; c < 2; ++c) {
      int cg = 2 * g + c;
      half8 pvf = c ? p1 : p0;
      if (cg < 17) {
        const unsigned short* src = (cg < 16)
            ? &pstB[lo * STR + cg * 32 + quad * 8]
            : &pstB[16 * STR + lo * 32 + quad * 8];
        oPB = __builtin_amdgcn_mfma_f32_16x16x32_f16(*(const half8*)src, pvf, oPB, 0, 0, 0);
      }
      if (cg >= 1) {
        int ksA = cg - 1;
        const unsigned short* src = (ksA < 16)
            ? &pstA[lo * STR + ksA * 32 + quad * 8]
            : &pstA[16 * STR + lo * 32 + quad * 8];
        oPA = __builtin_amdgcn_mfma_f32_16x16x32_f16(*(const half8*)src, pvf, oPA, 0, 0, 0);
      }
    }
  }

  // epilogue x2: single A-frag-major AwF, normalize here
  const int kf = h * 2 + (w >> 1);
  const int lhi = ((w & 1) * 2 + (lo >> 3)) * 16;
#pragma unroll
  for (int t = 0; t < 2; ++t) {
    int mc = b * 32 + itA + t * 2;
#pragma unroll
    for (int r = 0; r < 4; ++r) {
      float ov = t ? (oVB[r] + oPB[r]) * liB[r] : (oVA[r] + oPA[r]) * liA[r];
      size_t fl = (((size_t)mc * 16 + kf) * 64 + lhi + quad * 4 + r) * 8 + (lo & 7);
      AwF[fl] = f2h(ov);
    }
  }
}

// ---------------------------------------------------------------------------
// gemm_final: single-term fp16 MFMA, BK=64 staged. out = AwF @ WoF + bo.
// ---------------------------------------------------------------------------
__global__ __launch_bounds__(256, 2) void gemm_final(const unsigned short* __restrict__ AF,
                                                     const unsigned short* __restrict__ BF,
                                                     const float* __restrict__ bo,
                                                     float* __restrict__ out) {
  const int flat = blockIdx.x;
  const int xcd = flat & 7, g = flat >> 3;
  const int by = xcd * 8 + (g & 7), bx = g >> 3;
  const int bm = by * 64, bn = bx * 64;
  const int mc0 = bm >> 4, nc0 = bn >> 4;
  const int tid = threadIdx.x, w = tid >> 6, lane = tid & 63;
  const int lo = lane & 15, quad = lane >> 4;
  const int mh = (w >> 1) * 2, nh = (w & 1) * 2;

  __shared__ __align__(16) unsigned short stg[2][16 * 512];

  const unsigned short* srcArr = (w < 2) ? AF : BF;
  const int rowbase = ((w < 2) ? mc0 : nc0) + (w & 1) * 2;

#define STAGE2(buf, ks)                                                            \
  do {                                                                             \
    _Pragma("unroll") for (int t = 0; t < 4; ++t) {                                \
      gl_lds16(srcArr +                                                            \
                   (((size_t)(rowbase + (t >> 1)) * 16 + 2 * (ks) + (t & 1)) * 512) + \
                   lane * 8,                                                       \
               &stg[buf][(w * 4 + t) * 512]);                                      \
    }                                                                              \
  } while (0)

  f32x4 acc[2][2] = {};
  STAGE2(0, 0);
  int cur = 0;
#pragma unroll
  for (int ks = 0; ks < 8; ++ks) {
    __syncthreads();
    if (ks < 7) STAGE2(cur ^ 1, ks + 1);
#pragma unroll
    for (int kf = 0; kf < 2; ++kf) {
      half8 af[2], bf[2];
#pragma unroll
      for (int i = 0; i < 2; ++i)
        af[i] = *(const half8*)(&stg[cur][((mh + i) * 2 + kf) * 512 + lane * 8]);
#pragma unroll
      for (int j = 0; j < 2; ++j)
        bf[j] = *(const half8*)(&stg[cur][(8 + (nh + j) * 2 + kf) * 512 + lane * 8]);
#pragma unroll
      for (int i = 0; i < 2; ++i)
#pragma unroll
        for (int j = 0; j < 2; ++j)
          acc[i][j] = __builtin_amdgcn_mfma_f32_16x16x32_f16(af[i], bf[j], acc[i][j], 0, 0, 0);
    }
    cur ^= 1;
  }
#undef STAGE2

  const int mt = (w >> 1) * 32, nt = (w & 1) * 32;
#pragma unroll
  for (int i = 0; i < 2; ++i)
#pragma unroll
    for (int j = 0; j < 2; ++j) {
      int col = bn + nt + j * 16 + lo;
      float bb = bo[col];
#pragma unroll
      for (int r = 0; r < 4; ++r) {
        int row = bm + mt + i * 16 + quad * 4 + r;
        out[(size_t)row * DM + col] = acc[i][j][r] + bb;
      }
    }
}

// ---------------------------------------------------------------------------
extern "C" void kernel_launch(void* const* d_in, const int* in_sizes, int n_in,
                              void* d_out, int out_size, void* d_ws, size_t ws_size,
                              hipStream_t stream) {
  const float* X  = (const float*)d_in[0];
  const float* Wq = (const float*)d_in[1];
  const float* bq = (const float*)d_in[2];
  const float* Wk = (const float*)d_in[3];
  const float* bk = (const float*)d_in[4];
  const float* Wv = (const float*)d_in[5];
  const float* bv = (const float*)d_in[6];
  const float* Wo = (const float*)d_in[7];
  const float* bo = (const float*)d_in[8];
  const float* Pk = (const float*)d_in[9];
  const float* Pv = (const float*)d_in[10];
  float* out = (float*)d_out;

  char* p = (char*)d_ws;
  const size_t szX    = (size_t)Bc * Nseq * DM * 2;        // 4 MB
  const size_t szW    = (size_t)DM * DM * 2;               // 512 KB
  const size_t szPkt  = (size_t)Hh * 1040 * 4;
  const size_t szPvF2 = (size_t)2 * Hh * 4 * 32 * 512 * 2; // 2 MB
  const size_t szQKV  = (size_t)Bc * Hh * Nseq * 64 * 2;   // 4 MB
  unsigned short* XbF = (unsigned short*)p; p += szX;
  unsigned short* WqF = (unsigned short*)p; p += szW;
  unsigned short* WkF = (unsigned short*)p; p += szW;
  unsigned short* WvF = (unsigned short*)p; p += szW;
  unsigned short* WoF = (unsigned short*)p; p += szW;
  float*          Pkt = (float*)p;          p += (szPkt + 255) & ~(size_t)255;
  unsigned short* PvF2 = (unsigned short*)p; p += szPvF2;
  unsigned short* Qb  = (unsigned short*)p; p += szQKV;
  unsigned short* KF  = (unsigned short*)p; p += szQKV;
  unsigned short* VF  = (unsigned short*)p; p += szQKV;
  unsigned short* AwF = (unsigned short*)p; p += szX;

  dim3 blk(256);
  prep_all<<<dim3(2216), blk, 0, stream>>>(X, Wq, Wk, Wv, Wo, Pk, Pv,
                                           XbF, WqF, WkF, WvF, WoF, Pkt, PvF2);
  gemm_qkv<<<dim3(512), blk, 0, stream>>>(XbF, WqF, WkF, WvF, bq, bk, bv, Qb, KF, VF);
  attn_fused<<<dim3(1024), blk, 0, stream>>>(Qb, KF, VF, Pkt, PvF2, AwF);
  gemm_final<<<dim3(512), blk, 0, stream>>>(AwF, WoF, bo, out);
}